// Round 7
// baseline (327.833 us; speedup 1.0000x reference)
//
#include <hip/hip_runtime.h>
#include <math.h>

#define NODES   131072
#define EDGES   1048576
#define FDIM    32
#define HDIM    128
#define NGRAPH  512

typedef __attribute__((ext_vector_type(8))) short short8v;
typedef __attribute__((ext_vector_type(4))) float float4v;

__device__ __forceinline__ unsigned short f2bf(float f) {
    union { float f; unsigned int u; } v; v.f = f;
    unsigned int u = v.u;
    unsigned int r = (u + 0x7fffu + ((u >> 16) & 1u)) >> 16;   // RNE
    return (unsigned short)r;
}
__device__ __forceinline__ float bf2f(unsigned short u) {
    union { unsigned int u; float f; } v; v.u = ((unsigned int)u) << 16; return v.f;
}

// ---------------------------------------------------------------- k1: MFMA projection | hist fused
// blocks [0,1024): h0b (row-major, for gather) + h0p (C/D-frag-permuted, for k3a epilogue)
// blocks [1024,5120): degree histogram
__global__ __launch_bounds__(256) void k1_mfma(const float* __restrict__ x,
                                               const unsigned short* __restrict__ winfrag,
                                               unsigned short* __restrict__ h0b,
                                               unsigned short* __restrict__ h0p,
                                               const int* __restrict__ ei,
                                               int* __restrict__ count) {
    int b = blockIdx.x, t = threadIdx.x;
    if (b < 1024) {
        int wid = t >> 6, l = t & 63;
        int base = b * 128;

        const short8v* wf8 = (const short8v*)winfrag;
        short8v wfr[8];
#pragma unroll
        for (int c = 0; c < 8; ++c) wfr[c] = wf8[c * 64 + l];

#pragma unroll
        for (int s = 0; s < 2; ++s) {
            int strip = base + wid * 32 + s * 16;
            int row = strip + (l & 15);
            const float* xr = x + (size_t)row * FDIM + (l >> 4) * 8;
            float4 x0 = ((const float4*)xr)[0];
            float4 x1 = ((const float4*)xr)[1];
            short8v af;
            af[0] = (short)f2bf(x0.x); af[1] = (short)f2bf(x0.y);
            af[2] = (short)f2bf(x0.z); af[3] = (short)f2bf(x0.w);
            af[4] = (short)f2bf(x1.x); af[5] = (short)f2bf(x1.y);
            af[6] = (short)f2bf(x1.z); af[7] = (short)f2bf(x1.w);

            float4v acc[8];
#pragma unroll
            for (int c = 0; c < 8; ++c) acc[c] = (float4v){0.f, 0.f, 0.f, 0.f};
#pragma unroll
            for (int c = 0; c < 8; ++c)
                acc[c] = __builtin_amdgcn_mfma_f32_16x16x32_bf16(af, wfr[c], acc[c], 0, 0, 0);

            int rbase = strip + (l >> 4) * 4;   // C/D: col = lane&15, row = (lane>>4)*4 + reg
            int col = l & 15;
            // row-major store (gather consumes rows by src id)
#pragma unroll
            for (int r = 0; r < 4; ++r)
#pragma unroll
                for (int c = 0; c < 8; ++c)
                    h0b[(size_t)(rbase + r) * HDIM + c * 16 + col] = f2bf(acc[c][r]);
            // permuted store: lane-contiguous 64B, matches k3a's C/D fragment order
            short8v* pp = (short8v*)(h0p + (size_t)strip * HDIM + l * 32);
#pragma unroll
            for (int r = 0; r < 4; ++r) {
                short8v v;
#pragma unroll
                for (int c = 0; c < 8; ++c) v[c] = (short)f2bf(acc[c][r]);
                pp[r] = v;
            }
        }
    } else {
        int e = (b - 1024) * 256 + t;
        atomicAdd(&count[ei[EDGES + e]], 1);
    }
}

// ---------------------------------------------------------------- scans
__global__ __launch_bounds__(256) void kh_scanA(const int* __restrict__ count,
                                                int* __restrict__ offs,
                                                int* __restrict__ blockSums) {
    int b = blockIdx.x, t = threadIdx.x;
    int base = b * 512 + 2 * t;
    int a0 = count[base], a1 = count[base + 1];
    int pair = a0 + a1;
    __shared__ int sh[256];
    sh[t] = pair;
    __syncthreads();
    for (int off = 1; off < 256; off <<= 1) {
        int v = (t >= off) ? sh[t - off] : 0;
        __syncthreads();
        sh[t] += v;
        __syncthreads();
    }
    int excl = sh[t] - pair;
    offs[base] = excl;
    offs[base + 1] = excl + a0;
    if (t == 255) blockSums[b] = sh[255];
}

__global__ __launch_bounds__(256) void kh_scanC(int* __restrict__ offs,
                                                int* __restrict__ cursor,
                                                const int* __restrict__ bsums) {
    int b = blockIdx.x, t = threadIdx.x;
    __shared__ int sh[256];
    sh[t] = bsums[t];
    __syncthreads();
    for (int off = 1; off < 256; off <<= 1) {
        int v = (t >= off) ? sh[t - off] : 0;
        __syncthreads();
        sh[t] += v;
        __syncthreads();
    }
    int add = (b > 0) ? sh[b - 1] : 0;
    int base = b * 512 + 2 * t;
    int o0 = offs[base] + add, o1 = offs[base + 1] + add;
    offs[base] = o0; offs[base + 1] = o1;
    cursor[base] = o0; cursor[base + 1] = o1;
}

__global__ __launch_bounds__(256) void kh_fill(const int* __restrict__ ei,
                                               const float* __restrict__ ew,
                                               int* __restrict__ cursor,
                                               int2* __restrict__ bucket, int E) {
    int e = blockIdx.x * blockDim.x + threadIdx.x;
    if (e >= E) return;
    int src = ei[e];
    int tgt = ei[E + e];
    float w = ew[e];
    int pos = atomicAdd(&cursor[tgt], 1);
    bucket[pos] = make_int2(src, __float_as_int(w));
}

// ---------------------------------------------------------------- prep: wfrag | winfrag | cnt | gsum-zero
__global__ __launch_bounds__(256) void kprep(const float* __restrict__ Wmsg,
                                             const float* __restrict__ Win,
                                             unsigned short* __restrict__ wfrag,
                                             unsigned short* __restrict__ winfrag,
                                             const int* __restrict__ batch,
                                             int* __restrict__ cnt,
                                             float* __restrict__ gsum) {
    int b = blockIdx.x, t = threadIdx.x;
    if (b < 8) {
        int flat = b * 256 + t;
        int l = flat & 63;
        int fragid = flat >> 6;
        int c = fragid >> 2, kk = fragid & 3;
        int col = c * 16 + (l & 15);
        int k0 = kk * 32 + (l >> 4) * 8;
        short8v v;
#pragma unroll
        for (int j = 0; j < 8; ++j)
            v[j] = (short)f2bf(Wmsg[(k0 + j) * HDIM + col]);
        ((short8v*)wfrag)[flat] = v;
    } else if (b < 10) {
        int flat = (b - 8) * 256 + t;
        int l = flat & 63;
        int c = flat >> 6;
        int col = c * 16 + (l & 15);
        int k0 = (l >> 4) * 8;
        short8v v;
#pragma unroll
        for (int j = 0; j < 8; ++j)
            v[j] = (short)f2bf(Win[(k0 + j) * HDIM + col]);
        ((short8v*)winfrag)[flat] = v;
    } else if (b < 12) {
        int g = (b - 10) * 256 + t;
        if (g < NGRAPH) {
            int lo = 0, hi = NODES;
            while (lo < hi) { int m = (lo + hi) >> 1; if (batch[m] < g) lo = m + 1; else hi = m; }
            int start = lo;
            hi = NODES;
            while (lo < hi) { int m = (lo + hi) >> 1; if (batch[m] < g + 1) lo = m + 1; else hi = m; }
            cnt[g] = lo - start;
        }
    } else {
        float4* gz = (float4*)gsum;
        int idx = (b - 12) * 256 + t;
        for (int i = idx; i < 16384; i += 512) gz[i] = make_float4(0.f, 0.f, 0.f, 0.f);
    }
}

// ---------------------------------------------------------------- gather
__global__ __launch_bounds__(256) void kg_gather(const unsigned short* __restrict__ h0b,
                                                 const int* __restrict__ offs,
                                                 const int* __restrict__ cursor,
                                                 const int2* __restrict__ bucket,
                                                 unsigned short* __restrict__ msgb, int N) {
    long long gid = blockIdx.x * (long long)blockDim.x + threadIdx.x;
    int n = (int)(gid >> 6);
    if (n >= N) return;
    int l = (int)(gid & 63);
    int beg = offs[n];
    int end = cursor[n];
    float ax = 0.f, ay = 0.f;
    int j = beg;
    for (; j + 4 <= end; j += 4) {
        int2 e0 = bucket[j], e1 = bucket[j + 1], e2 = bucket[j + 2], e3 = bucket[j + 3];
        unsigned int u0 = ((const unsigned int*)(h0b + (size_t)e0.x * HDIM))[l];
        unsigned int u1 = ((const unsigned int*)(h0b + (size_t)e1.x * HDIM))[l];
        unsigned int u2 = ((const unsigned int*)(h0b + (size_t)e2.x * HDIM))[l];
        unsigned int u3 = ((const unsigned int*)(h0b + (size_t)e3.x * HDIM))[l];
        float w0 = __int_as_float(e0.y), w1 = __int_as_float(e1.y);
        float w2 = __int_as_float(e2.y), w3 = __int_as_float(e3.y);
        ax = fmaf(__uint_as_float(u0 << 16), w0, ax); ay = fmaf(__uint_as_float(u0 & 0xFFFF0000u), w0, ay);
        ax = fmaf(__uint_as_float(u1 << 16), w1, ax); ay = fmaf(__uint_as_float(u1 & 0xFFFF0000u), w1, ay);
        ax = fmaf(__uint_as_float(u2 << 16), w2, ax); ay = fmaf(__uint_as_float(u2 & 0xFFFF0000u), w2, ay);
        ax = fmaf(__uint_as_float(u3 << 16), w3, ax); ay = fmaf(__uint_as_float(u3 & 0xFFFF0000u), w3, ay);
    }
    for (; j < end; ++j) {
        int2 e0 = bucket[j];
        unsigned int u0 = ((const unsigned int*)(h0b + (size_t)e0.x * HDIM))[l];
        float w0 = __int_as_float(e0.y);
        ax = fmaf(__uint_as_float(u0 << 16), w0, ax); ay = fmaf(__uint_as_float(u0 & 0xFFFF0000u), w0, ay);
    }
    ushort2 o; o.x = f2bf(ax); o.y = f2bf(ay);
    ((ushort2*)(msgb + (size_t)n * HDIM))[l] = o;
}

// ---------------------------------------------------------------- k3a: MFMA GEMM + relu + fused pool
// h0 read via the permuted copy h0p: 4 coalesced b128 loads per strip (no scalar chains).
__global__ __launch_bounds__(256) void k3a_mfma_pool(const unsigned short* __restrict__ msgb,
                                                     const unsigned short* __restrict__ h0p,
                                                     const unsigned short* __restrict__ wfrag,
                                                     const int* __restrict__ batch,
                                                     float* __restrict__ gsum) {
    __shared__ __align__(16) unsigned short blds[32 * 64 * 8];  // 32KB
    __shared__ float pool[8][HDIM];                              // 4KB
    __shared__ int batch_lds[128];

    int t = threadIdx.x;
    int wid = t >> 6, l = t & 63;
    int base = blockIdx.x * 128;

    {
        const uint4* s = (const uint4*)wfrag;
        uint4* d = (uint4*)blds;
#pragma unroll
        for (int i = 0; i < 8; ++i) d[t + 256 * i] = s[t + 256 * i];
    }
    if (t < 128) batch_lds[t] = batch[base + t];
    {
        float* pf = (float*)pool;
        for (int i = t; i < 8 * HDIM; i += 256) pf[i] = 0.f;
    }
    __syncthreads();

    int bfirst = batch_lds[0];
    int blast  = batch_lds[127];
    int span = blast - bfirst + 1;
    bool lds_pool = (span <= 8);

    const short8v* Bl = (const short8v*)blds;
    int col = l & 15;
    int rsub = (l >> 4) * 4;

#pragma unroll
    for (int s = 0; s < 2; ++s) {
        int strip = base + wid * 32 + s * 16;
        // A fragments (coalesced b128)
        const short8v* mrow = (const short8v*)(msgb + (size_t)(strip + col) * HDIM);
        short8v af[4];
#pragma unroll
        for (int kk = 0; kk < 4; ++kk)
            af[kk] = mrow[kk * 4 + (l >> 4)];
        // h0 in C/D order (coalesced b128, independent of atomics -> issued early)
        const short8v* hp = (const short8v*)(h0p + (size_t)strip * HDIM + l * 32);
        short8v h0r[4];
#pragma unroll
        for (int r = 0; r < 4; ++r) h0r[r] = hp[r];

        float4v acc[8];
#pragma unroll
        for (int c = 0; c < 8; ++c) acc[c] = (float4v){0.f, 0.f, 0.f, 0.f};
#pragma unroll
        for (int kk = 0; kk < 4; ++kk)
#pragma unroll
            for (int c = 0; c < 8; ++c)
                acc[c] = __builtin_amdgcn_mfma_f32_16x16x32_bf16(af[kk], Bl[(c * 4 + kk) * 64 + l], acc[c], 0, 0, 0);

        int rbase = strip + rsub;
        if (lds_pool) {
#pragma unroll
            for (int r = 0; r < 4; ++r) {
                int g = batch_lds[rbase + r - base] - bfirst;
#pragma unroll
                for (int c = 0; c < 8; ++c) {
                    float hv = fmaxf(bf2f((unsigned short)h0r[r][c]) + acc[c][r], 0.f);
                    atomicAdd(&pool[g][c * 16 + col], hv);
                }
            }
        } else {
#pragma unroll
            for (int r = 0; r < 4; ++r) {
                int g = batch_lds[rbase + r - base];
#pragma unroll
                for (int c = 0; c < 8; ++c) {
                    float hv = fmaxf(bf2f((unsigned short)h0r[r][c]) + acc[c][r], 0.f);
                    atomicAdd(&gsum[(size_t)g * HDIM + c * 16 + col], hv);
                }
            }
        }
    }

    __syncthreads();
    if (lds_pool) {
        int cc = t & 127;
        for (int s = t >> 7; s < span; s += 2)
            atomicAdd(&gsum[(size_t)(bfirst + s) * HDIM + cc], pool[s][cc]);
    }
}

// ---------------------------------------------------------------- k4a: backbone + value head; writes s2g
__global__ __launch_bounds__(128) void k4a_backbone(const float* __restrict__ gsum,
                                                    const int* __restrict__ cnt,
                                                    const float* __restrict__ W1,
                                                    const float* __restrict__ W2,
                                                    const float* __restrict__ Wv1,
                                                    const float* __restrict__ Wv2,
                                                    float* __restrict__ s2g,
                                                    float* __restrict__ out) {
    int g = blockIdx.x;
    int t = threadIdx.x;
    __shared__ float gv[HDIM];
    __shared__ float s1[HDIM];
    __shared__ float s2v[64];
    __shared__ float v1[32];

    {
        int c = cnt[g];
        gv[t] = (c > 0) ? gsum[(size_t)g * HDIM + t] / (float)c : 0.f;
    }
    __syncthreads();

    {
        float s = 0.f;
#pragma unroll 8
        for (int k = 0; k < HDIM; ++k)
            s = fmaf(gv[k], W1[k * HDIM + t] + W1[(k + HDIM) * HDIM + t], s);
        s1[t] = fmaxf(s, 0.f);
    }
    __syncthreads();

    if (t < 64) {
        float s = 0.f;
#pragma unroll 8
        for (int k = 0; k < HDIM; ++k)
            s = fmaf(s1[k], W2[k * 64 + t], s);
        float sv = fmaxf(s, 0.f);
        s2v[t] = sv;
        s2g[(size_t)g * 64 + t] = sv;
    }
    __syncthreads();

    if (t < 32) {
        float s = 0.f;
#pragma unroll 8
        for (int k = 0; k < 64; ++k)
            s = fmaf(s2v[k], Wv1[k * 32 + t], s);
        v1[t] = fmaxf(s, 0.f);
    }
    __syncthreads();
    if (t == 0) {
        float s = 0.f;
#pragma unroll
        for (int k = 0; k < 32; ++k)
            s = fmaf(v1[k], Wv2[k], s);
        out[1028608 + (size_t)g] = tanhf(s);
    }
}

// ---------------------------------------------------------------- k4b: logits GEMM [512,64]@[64,2009]
__global__ __launch_bounds__(256) void k4b_logits(const float* __restrict__ s2g,
                                                  const float* __restrict__ Wa,
                                                  const float* __restrict__ Ws,
                                                  const float* __restrict__ Wt,
                                                  const float* __restrict__ Wact,
                                                  float* __restrict__ out) {
    int ctile = blockIdx.x & 7;
    int gbase = (blockIdx.x >> 3) * 16;
    int t = threadIdx.x;
    int col = ctile * 256 + t;

    __shared__ float4 s2s4[16][16];
    {
        int g = t >> 4, q = t & 15;
        s2s4[g][q] = ((const float4*)(s2g + (size_t)(gbase + g) * 64))[q];
    }

    bool valid = (col < 2009);
    const float* W = Wa; int colc = 0, ncol = 5; size_t hb = 0;
    if (col < 5)        { W = Wa;   colc = col;        ncol = 5;    hb = 0; }
    else if (col < 1005){ W = Ws;   colc = col - 5;    ncol = 1000; hb = 2560; }
    else if (col < 2005){ W = Wt;   colc = col - 1005; ncol = 1000; hb = 514560; }
    else                { W = Wact; colc = col - 2005; ncol = 4;    hb = 1026560; }

    float wr[64];
#pragma unroll
    for (int k = 0; k < 64; ++k)
        wr[k] = valid ? W[(size_t)k * ncol + colc] : 0.f;
    __syncthreads();

    for (int gg = 0; gg < 16; ++gg) {
        const float4* s4 = (const float4*)s2s4[gg];
        float a = 0.f;
#pragma unroll
        for (int q = 0; q < 16; ++q) {
            float4 v = s4[q];
            a = fmaf(v.x, wr[4 * q + 0], a);
            a = fmaf(v.y, wr[4 * q + 1], a);
            a = fmaf(v.z, wr[4 * q + 2], a);
            a = fmaf(v.w, wr[4 * q + 3], a);
        }
        if (valid) out[hb + (size_t)(gbase + gg) * ncol + colc] = a;
    }
}

// ----------------------------------------------------------------
extern "C" void kernel_launch(void* const* d_in, const int* in_sizes, int n_in,
                              void* d_out, int out_size, void* d_ws, size_t ws_size,
                              hipStream_t stream) {
    const float* x     = (const float*)d_in[0];
    const int*   ei    = (const int*)d_in[1];
    const float* ew    = (const float*)d_in[2];
    const int*   batch = (const int*)d_in[4];
    const float* Win   = (const float*)d_in[6];
    const float* Wmsg  = (const float*)d_in[7];
    const float* W1    = (const float*)d_in[8];
    const float* W2    = (const float*)d_in[9];
    const float* Wa    = (const float*)d_in[10];
    const float* Ws    = (const float*)d_in[11];
    const float* Wt    = (const float*)d_in[12];
    const float* Wact  = (const float*)d_in[13];
    const float* Wv1   = (const float*)d_in[14];
    const float* Wv2   = (const float*)d_in[15];
    float* out = (float*)d_out;

    char* p = (char*)d_ws;
    const size_t nb = (size_t)NODES * HDIM * 2;                  // 32 MB
    unsigned short* h0b    = (unsigned short*)p;  p += nb;
    unsigned short* msgb   = (unsigned short*)p;  p += nb;
    unsigned short* h0p    = (unsigned short*)p;  p += nb;
    float*          gsum   = (float*)p;           p += (size_t)NGRAPH * HDIM * 4;
    float*          s2g    = (float*)p;           p += (size_t)NGRAPH * 64 * 4;
    unsigned short* wfrag  = (unsigned short*)p;  p += 32 * 64 * 16;
    unsigned short* winfrag= (unsigned short*)p;  p += 8 * 64 * 16;
    int*            count  = (int*)p;             p += (size_t)NODES * 4;
    int*            offs   = (int*)p;             p += (size_t)NODES * 4;
    int*            cursor = (int*)p;             p += (size_t)NODES * 4;
    int2*           bucket = (int2*)p;            p += (size_t)EDGES * 8;
    int*            cnt    = (int*)p;             p += (size_t)NGRAPH * 4;
    int*            bsums  = (int*)p;             p += 256 * 4;

    hipMemsetAsync(count, 0, (size_t)NODES * 4, stream);

    kprep   <<<14, 256, 0, stream>>>(Wmsg, Win, wfrag, winfrag, batch, cnt, gsum);
    k1_mfma <<<5120, 256, 0, stream>>>(x, winfrag, h0b, h0p, ei, count);
    kh_scanA<<<256, 256, 0, stream>>>(count, offs, bsums);
    kh_scanC<<<256, 256, 0, stream>>>(offs, cursor, bsums);
    kh_fill <<<EDGES / 256, 256, 0, stream>>>(ei, ew, cursor, bucket, EDGES);

    kg_gather<<<(NODES * 64) / 256, 256, 0, stream>>>(h0b, offs, cursor, bucket, msgb, NODES);

    k3a_mfma_pool<<<NODES / 128, 256, 0, stream>>>(msgb, h0p, wfrag, batch, gsum);

    k4a_backbone<<<NGRAPH, 128, 0, stream>>>(gsum, cnt, W1, W2, Wv1, Wv2, s2g, out);
    k4b_logits  <<<256, 256, 0, stream>>>(s2g, Wa, Ws, Wt, Wact, out);
}

// Round 8
// 248.971 us; speedup vs baseline: 1.3168x; 1.3168x over previous
//
#include <hip/hip_runtime.h>
#include <math.h>

#define NODES   131072
#define EDGES   1048576
#define FDIM    32
#define HDIM    128
#define NGRAPH  512

typedef __attribute__((ext_vector_type(8))) short short8v;
typedef __attribute__((ext_vector_type(4))) float float4v;

__device__ __forceinline__ unsigned short f2bf(float f) {
    union { float f; unsigned int u; } v; v.f = f;
    unsigned int u = v.u;
    unsigned int r = (u + 0x7fffu + ((u >> 16) & 1u)) >> 16;   // RNE
    return (unsigned short)r;
}
__device__ __forceinline__ float bf2f(unsigned short u) {
    union { unsigned int u; float f; } v; v.u = ((unsigned int)u) << 16; return v.f;
}

// ---------------------------------------------------------------- k1: MFMA projection | hist fused
__global__ __launch_bounds__(256) void k1_mfma(const float* __restrict__ x,
                                               const unsigned short* __restrict__ winfrag,
                                               unsigned short* __restrict__ h0b,
                                               unsigned short* __restrict__ h0p,
                                               const int* __restrict__ ei,
                                               int* __restrict__ count) {
    int b = blockIdx.x, t = threadIdx.x;
    if (b < 1024) {
        int wid = t >> 6, l = t & 63;
        int base = b * 128;

        const short8v* wf8 = (const short8v*)winfrag;
        short8v wfr[8];
#pragma unroll
        for (int c = 0; c < 8; ++c) wfr[c] = wf8[c * 64 + l];

#pragma unroll
        for (int s = 0; s < 2; ++s) {
            int strip = base + wid * 32 + s * 16;
            int row = strip + (l & 15);
            const float* xr = x + (size_t)row * FDIM + (l >> 4) * 8;
            float4 x0 = ((const float4*)xr)[0];
            float4 x1 = ((const float4*)xr)[1];
            short8v af;
            af[0] = (short)f2bf(x0.x); af[1] = (short)f2bf(x0.y);
            af[2] = (short)f2bf(x0.z); af[3] = (short)f2bf(x0.w);
            af[4] = (short)f2bf(x1.x); af[5] = (short)f2bf(x1.y);
            af[6] = (short)f2bf(x1.z); af[7] = (short)f2bf(x1.w);

            float4v acc[8];
#pragma unroll
            for (int c = 0; c < 8; ++c) acc[c] = (float4v){0.f, 0.f, 0.f, 0.f};
#pragma unroll
            for (int c = 0; c < 8; ++c)
                acc[c] = __builtin_amdgcn_mfma_f32_16x16x32_bf16(af, wfr[c], acc[c], 0, 0, 0);

            int rbase = strip + (l >> 4) * 4;   // C/D: col = lane&15, row = (lane>>4)*4 + reg
            int col = l & 15;
#pragma unroll
            for (int r = 0; r < 4; ++r)
#pragma unroll
                for (int c = 0; c < 8; ++c)
                    h0b[(size_t)(rbase + r) * HDIM + c * 16 + col] = f2bf(acc[c][r]);
            short8v* pp = (short8v*)(h0p + (size_t)strip * HDIM + l * 32);
#pragma unroll
            for (int r = 0; r < 4; ++r) {
                short8v v;
#pragma unroll
                for (int c = 0; c < 8; ++c) v[c] = (short)f2bf(acc[c][r]);
                pp[r] = v;
            }
        }
    } else {
        int e = (b - 1024) * 256 + t;
        atomicAdd(&count[ei[EDGES + e]], 1);
    }
}

// ---------------------------------------------------------------- scans
__global__ __launch_bounds__(256) void kh_scanA(const int* __restrict__ count,
                                                int* __restrict__ offs,
                                                int* __restrict__ blockSums) {
    int b = blockIdx.x, t = threadIdx.x;
    int base = b * 512 + 2 * t;
    int a0 = count[base], a1 = count[base + 1];
    int pair = a0 + a1;
    __shared__ int sh[256];
    sh[t] = pair;
    __syncthreads();
    for (int off = 1; off < 256; off <<= 1) {
        int v = (t >= off) ? sh[t - off] : 0;
        __syncthreads();
        sh[t] += v;
        __syncthreads();
    }
    int excl = sh[t] - pair;
    offs[base] = excl;
    offs[base + 1] = excl + a0;
    if (t == 255) blockSums[b] = sh[255];
}

__global__ __launch_bounds__(256) void kh_scanC(int* __restrict__ offs,
                                                int* __restrict__ cursor,
                                                const int* __restrict__ bsums) {
    int b = blockIdx.x, t = threadIdx.x;
    __shared__ int sh[256];
    sh[t] = bsums[t];
    __syncthreads();
    for (int off = 1; off < 256; off <<= 1) {
        int v = (t >= off) ? sh[t - off] : 0;
        __syncthreads();
        sh[t] += v;
        __syncthreads();
    }
    int add = (b > 0) ? sh[b - 1] : 0;
    int base = b * 512 + 2 * t;
    int o0 = offs[base] + add, o1 = offs[base + 1] + add;
    offs[base] = o0; offs[base + 1] = o1;
    cursor[base] = o0; cursor[base + 1] = o1;
}

__global__ __launch_bounds__(256) void kh_fill(const int* __restrict__ ei,
                                               const float* __restrict__ ew,
                                               int* __restrict__ cursor,
                                               int2* __restrict__ bucket, int E) {
    int e = blockIdx.x * blockDim.x + threadIdx.x;
    if (e >= E) return;
    int src = ei[e];
    int tgt = ei[E + e];
    float w = ew[e];
    int pos = atomicAdd(&cursor[tgt], 1);
    bucket[pos] = make_int2(src, __float_as_int(w));
}

// ---------------------------------------------------------------- prep: wfrag | winfrag | cnt | gsum-zero
__global__ __launch_bounds__(256) void kprep(const float* __restrict__ Wmsg,
                                             const float* __restrict__ Win,
                                             unsigned short* __restrict__ wfrag,
                                             unsigned short* __restrict__ winfrag,
                                             const int* __restrict__ batch,
                                             int* __restrict__ cnt,
                                             float* __restrict__ gsum) {
    int b = blockIdx.x, t = threadIdx.x;
    if (b < 8) {
        int flat = b * 256 + t;
        int l = flat & 63;
        int fragid = flat >> 6;
        int c = fragid >> 2, kk = fragid & 3;
        int col = c * 16 + (l & 15);
        int k0 = kk * 32 + (l >> 4) * 8;
        short8v v;
#pragma unroll
        for (int j = 0; j < 8; ++j)
            v[j] = (short)f2bf(Wmsg[(k0 + j) * HDIM + col]);
        ((short8v*)wfrag)[flat] = v;
    } else if (b < 10) {
        int flat = (b - 8) * 256 + t;
        int l = flat & 63;
        int c = flat >> 6;
        int col = c * 16 + (l & 15);
        int k0 = (l >> 4) * 8;
        short8v v;
#pragma unroll
        for (int j = 0; j < 8; ++j)
            v[j] = (short)f2bf(Win[(k0 + j) * HDIM + col]);
        ((short8v*)winfrag)[flat] = v;
    } else if (b < 12) {
        int g = (b - 10) * 256 + t;
        if (g < NGRAPH) {
            int lo = 0, hi = NODES;
            while (lo < hi) { int m = (lo + hi) >> 1; if (batch[m] < g) lo = m + 1; else hi = m; }
            int start = lo;
            hi = NODES;
            while (lo < hi) { int m = (lo + hi) >> 1; if (batch[m] < g + 1) lo = m + 1; else hi = m; }
            cnt[g] = lo - start;
        }
    } else {
        float4* gz = (float4*)gsum;
        int idx = (b - 12) * 256 + t;
        for (int i = idx; i < 16384; i += 512) gz[i] = make_float4(0.f, 0.f, 0.f, 0.f);
    }
}

// ---------------------------------------------------------------- gather
__global__ __launch_bounds__(256) void kg_gather(const unsigned short* __restrict__ h0b,
                                                 const int* __restrict__ offs,
                                                 const int* __restrict__ cursor,
                                                 const int2* __restrict__ bucket,
                                                 unsigned short* __restrict__ msgb, int N) {
    long long gid = blockIdx.x * (long long)blockDim.x + threadIdx.x;
    int n = (int)(gid >> 6);
    if (n >= N) return;
    int l = (int)(gid & 63);
    int beg = offs[n];
    int end = cursor[n];
    float ax = 0.f, ay = 0.f;
    int j = beg;
    for (; j + 4 <= end; j += 4) {
        int2 e0 = bucket[j], e1 = bucket[j + 1], e2 = bucket[j + 2], e3 = bucket[j + 3];
        unsigned int u0 = ((const unsigned int*)(h0b + (size_t)e0.x * HDIM))[l];
        unsigned int u1 = ((const unsigned int*)(h0b + (size_t)e1.x * HDIM))[l];
        unsigned int u2 = ((const unsigned int*)(h0b + (size_t)e2.x * HDIM))[l];
        unsigned int u3 = ((const unsigned int*)(h0b + (size_t)e3.x * HDIM))[l];
        float w0 = __int_as_float(e0.y), w1 = __int_as_float(e1.y);
        float w2 = __int_as_float(e2.y), w3 = __int_as_float(e3.y);
        ax = fmaf(__uint_as_float(u0 << 16), w0, ax); ay = fmaf(__uint_as_float(u0 & 0xFFFF0000u), w0, ay);
        ax = fmaf(__uint_as_float(u1 << 16), w1, ax); ay = fmaf(__uint_as_float(u1 & 0xFFFF0000u), w1, ay);
        ax = fmaf(__uint_as_float(u2 << 16), w2, ax); ay = fmaf(__uint_as_float(u2 & 0xFFFF0000u), w2, ay);
        ax = fmaf(__uint_as_float(u3 << 16), w3, ax); ay = fmaf(__uint_as_float(u3 & 0xFFFF0000u), w3, ay);
    }
    for (; j < end; ++j) {
        int2 e0 = bucket[j];
        unsigned int u0 = ((const unsigned int*)(h0b + (size_t)e0.x * HDIM))[l];
        float w0 = __int_as_float(e0.y);
        ax = fmaf(__uint_as_float(u0 << 16), w0, ax); ay = fmaf(__uint_as_float(u0 & 0xFFFF0000u), w0, ay);
    }
    ushort2 o; o.x = f2bf(ax); o.y = f2bf(ay);
    ((ushort2*)(msgb + (size_t)n * HDIM))[l] = o;
}

// ---------------------------------------------------------------- k3a: MFMA GEMM + relu + pool
// span<=2 fast path: register masked reduce + shfl_xor; NO per-element atomics.
__global__ __launch_bounds__(256) void k3a_mfma_pool(const unsigned short* __restrict__ msgb,
                                                     const unsigned short* __restrict__ h0p,
                                                     const unsigned short* __restrict__ wfrag,
                                                     const int* __restrict__ batch,
                                                     float* __restrict__ gsum) {
    __shared__ __align__(16) unsigned short blds[32 * 64 * 8];  // 32KB
    __shared__ float pool[8][HDIM];                              // 4KB (fast path: [4][2][128])
    __shared__ int batch_lds[128];

    int t = threadIdx.x;
    int wid = t >> 6, l = t & 63;
    int base = blockIdx.x * 128;

    {
        const uint4* sp = (const uint4*)wfrag;
        uint4* d = (uint4*)blds;
#pragma unroll
        for (int i = 0; i < 8; ++i) d[t + 256 * i] = sp[t + 256 * i];
    }
    if (t < 128) batch_lds[t] = batch[base + t];
    __syncthreads();

    int bfirst = batch_lds[0];
    int blast  = batch_lds[127];
    int span = blast - bfirst + 1;

    const short8v* Bl = (const short8v*)blds;
    int col = l & 15;

    if (span <= 2) {
        // -------- fast path: no atomics except 1 global add per (col,graph)
        float pa[8], pb[8];
#pragma unroll
        for (int c = 0; c < 8; ++c) { pa[c] = 0.f; pb[c] = 0.f; }

#pragma unroll
        for (int s = 0; s < 2; ++s) {
            int strip = base + wid * 32 + s * 16;
            const short8v* mrow = (const short8v*)(msgb + (size_t)(strip + col) * HDIM);
            short8v af[4];
#pragma unroll
            for (int kk = 0; kk < 4; ++kk) af[kk] = mrow[kk * 4 + (l >> 4)];
            const short8v* hp = (const short8v*)(h0p + (size_t)strip * HDIM + l * 32);
            short8v h0r[4];
#pragma unroll
            for (int r = 0; r < 4; ++r) h0r[r] = hp[r];

            float4v acc[8];
#pragma unroll
            for (int c = 0; c < 8; ++c) acc[c] = (float4v){0.f, 0.f, 0.f, 0.f};
#pragma unroll
            for (int kk = 0; kk < 4; ++kk)
#pragma unroll
                for (int c = 0; c < 8; ++c)
                    acc[c] = __builtin_amdgcn_mfma_f32_16x16x32_bf16(af[kk], Bl[(c * 4 + kk) * 64 + l], acc[c], 0, 0, 0);

            int rbase = strip + (l >> 4) * 4;
#pragma unroll
            for (int r = 0; r < 4; ++r) {
                bool isA = (batch_lds[rbase + r - base] == bfirst);
#pragma unroll
                for (int c = 0; c < 8; ++c) {
                    float hv = fmaxf(bf2f((unsigned short)h0r[r][c]) + acc[c][r], 0.f);
                    pa[c] += isA ? hv : 0.f;
                    pb[c] += isA ? 0.f : hv;
                }
            }
        }
        // reduce over the 4 row-lane-groups (lane bits 4,5)
#pragma unroll
        for (int c = 0; c < 8; ++c) {
            pa[c] += __shfl_xor(pa[c], 16);
            pa[c] += __shfl_xor(pa[c], 32);
            pb[c] += __shfl_xor(pb[c], 16);
            pb[c] += __shfl_xor(pb[c], 32);
        }
        float (*p2)[2][HDIM] = (float (*)[2][HDIM])pool;
        if (l < 16) {
#pragma unroll
            for (int c = 0; c < 8; ++c) {
                p2[wid][0][c * 16 + l] = pa[c];
                p2[wid][1][c * 16 + l] = pb[c];
            }
        }
        __syncthreads();
        int cc = t & 127, sidx = t >> 7;
        if (sidx < span) {
            float v = p2[0][sidx][cc] + p2[1][sidx][cc] + p2[2][sidx][cc] + p2[3][sidx][cc];
            atomicAdd(&gsum[(size_t)(bfirst + sidx) * HDIM + cc], v);
        }
    } else {
        // -------- rare fallback: LDS-atomic pool (span<=8) or global atomics
        bool lds_pool = (span <= 8);
        if (lds_pool) {
            float* pf = (float*)pool;
            for (int i = t; i < 8 * HDIM; i += 256) pf[i] = 0.f;
        }
        __syncthreads();

        int rsub = (l >> 4) * 4;
#pragma unroll
        for (int s = 0; s < 2; ++s) {
            int strip = base + wid * 32 + s * 16;
            const short8v* mrow = (const short8v*)(msgb + (size_t)(strip + col) * HDIM);
            short8v af[4];
#pragma unroll
            for (int kk = 0; kk < 4; ++kk) af[kk] = mrow[kk * 4 + (l >> 4)];
            const short8v* hp = (const short8v*)(h0p + (size_t)strip * HDIM + l * 32);
            short8v h0r[4];
#pragma unroll
            for (int r = 0; r < 4; ++r) h0r[r] = hp[r];

            float4v acc[8];
#pragma unroll
            for (int c = 0; c < 8; ++c) acc[c] = (float4v){0.f, 0.f, 0.f, 0.f};
#pragma unroll
            for (int kk = 0; kk < 4; ++kk)
#pragma unroll
                for (int c = 0; c < 8; ++c)
                    acc[c] = __builtin_amdgcn_mfma_f32_16x16x32_bf16(af[kk], Bl[(c * 4 + kk) * 64 + l], acc[c], 0, 0, 0);

            int rbase = strip + rsub;
            if (lds_pool) {
#pragma unroll
                for (int r = 0; r < 4; ++r) {
                    int g = batch_lds[rbase + r - base] - bfirst;
#pragma unroll
                    for (int c = 0; c < 8; ++c) {
                        float hv = fmaxf(bf2f((unsigned short)h0r[r][c]) + acc[c][r], 0.f);
                        atomicAdd(&pool[g][c * 16 + col], hv);
                    }
                }
            } else {
#pragma unroll
                for (int r = 0; r < 4; ++r) {
                    int g = batch_lds[rbase + r - base];
#pragma unroll
                    for (int c = 0; c < 8; ++c) {
                        float hv = fmaxf(bf2f((unsigned short)h0r[r][c]) + acc[c][r], 0.f);
                        atomicAdd(&gsum[(size_t)g * HDIM + c * 16 + col], hv);
                    }
                }
            }
        }
        __syncthreads();
        if (lds_pool) {
            int cc = t & 127;
            for (int s2 = t >> 7; s2 < span; s2 += 2)
                atomicAdd(&gsum[(size_t)(bfirst + s2) * HDIM + cc], pool[s2][cc]);
        }
    }
}

// ---------------------------------------------------------------- k4a: backbone + value head; writes s2g
__global__ __launch_bounds__(128) void k4a_backbone(const float* __restrict__ gsum,
                                                    const int* __restrict__ cnt,
                                                    const float* __restrict__ W1,
                                                    const float* __restrict__ W2,
                                                    const float* __restrict__ Wv1,
                                                    const float* __restrict__ Wv2,
                                                    float* __restrict__ s2g,
                                                    float* __restrict__ out) {
    int g = blockIdx.x;
    int t = threadIdx.x;
    __shared__ float gv[HDIM];
    __shared__ float s1[HDIM];
    __shared__ float s2v[64];
    __shared__ float v1[32];

    {
        int c = cnt[g];
        gv[t] = (c > 0) ? gsum[(size_t)g * HDIM + t] / (float)c : 0.f;
    }
    __syncthreads();

    {
        float s = 0.f;
#pragma unroll 8
        for (int k = 0; k < HDIM; ++k)
            s = fmaf(gv[k], W1[k * HDIM + t] + W1[(k + HDIM) * HDIM + t], s);
        s1[t] = fmaxf(s, 0.f);
    }
    __syncthreads();

    if (t < 64) {
        float s = 0.f;
#pragma unroll 8
        for (int k = 0; k < HDIM; ++k)
            s = fmaf(s1[k], W2[k * 64 + t], s);
        float sv = fmaxf(s, 0.f);
        s2v[t] = sv;
        s2g[(size_t)g * 64 + t] = sv;
    }
    __syncthreads();

    if (t < 32) {
        float s = 0.f;
#pragma unroll 8
        for (int k = 0; k < 64; ++k)
            s = fmaf(s2v[k], Wv1[k * 32 + t], s);
        v1[t] = fmaxf(s, 0.f);
    }
    __syncthreads();
    if (t == 0) {
        float s = 0.f;
#pragma unroll
        for (int k = 0; k < 32; ++k)
            s = fmaf(v1[k], Wv2[k], s);
        out[1028608 + (size_t)g] = tanhf(s);
    }
}

// ---------------------------------------------------------------- k4b: logits GEMM [512,64]@[64,2009]
__global__ __launch_bounds__(256) void k4b_logits(const float* __restrict__ s2g,
                                                  const float* __restrict__ Wa,
                                                  const float* __restrict__ Ws,
                                                  const float* __restrict__ Wt,
                                                  const float* __restrict__ Wact,
                                                  float* __restrict__ out) {
    int ctile = blockIdx.x & 7;
    int gbase = (blockIdx.x >> 3) * 16;
    int t = threadIdx.x;
    int col = ctile * 256 + t;

    __shared__ float4 s2s4[16][16];
    {
        int g = t >> 4, q = t & 15;
        s2s4[g][q] = ((const float4*)(s2g + (size_t)(gbase + g) * 64))[q];
    }

    bool valid = (col < 2009);
    const float* W = Wa; int colc = 0, ncol = 5; size_t hb = 0;
    if (col < 5)        { W = Wa;   colc = col;        ncol = 5;    hb = 0; }
    else if (col < 1005){ W = Ws;   colc = col - 5;    ncol = 1000; hb = 2560; }
    else if (col < 2005){ W = Wt;   colc = col - 1005; ncol = 1000; hb = 514560; }
    else                { W = Wact; colc = col - 2005; ncol = 4;    hb = 1026560; }

    float wr[64];
#pragma unroll
    for (int k = 0; k < 64; ++k)
        wr[k] = valid ? W[(size_t)k * ncol + colc] : 0.f;
    __syncthreads();

    for (int gg = 0; gg < 16; ++gg) {
        const float4* s4 = (const float4*)s2s4[gg];
        float a = 0.f;
#pragma unroll
        for (int q = 0; q < 16; ++q) {
            float4 v = s4[q];
            a = fmaf(v.x, wr[4 * q + 0], a);
            a = fmaf(v.y, wr[4 * q + 1], a);
            a = fmaf(v.z, wr[4 * q + 2], a);
            a = fmaf(v.w, wr[4 * q + 3], a);
        }
        if (valid) out[hb + (size_t)(gbase + gg) * ncol + colc] = a;
    }
}

// ----------------------------------------------------------------
extern "C" void kernel_launch(void* const* d_in, const int* in_sizes, int n_in,
                              void* d_out, int out_size, void* d_ws, size_t ws_size,
                              hipStream_t stream) {
    const float* x     = (const float*)d_in[0];
    const int*   ei    = (const int*)d_in[1];
    const float* ew    = (const float*)d_in[2];
    const int*   batch = (const int*)d_in[4];
    const float* Win   = (const float*)d_in[6];
    const float* Wmsg  = (const float*)d_in[7];
    const float* W1    = (const float*)d_in[8];
    const float* W2    = (const float*)d_in[9];
    const float* Wa    = (const float*)d_in[10];
    const float* Ws    = (const float*)d_in[11];
    const float* Wt    = (const float*)d_in[12];
    const float* Wact  = (const float*)d_in[13];
    const float* Wv1   = (const float*)d_in[14];
    const float* Wv2   = (const float*)d_in[15];
    float* out = (float*)d_out;

    char* p = (char*)d_ws;
    const size_t nb = (size_t)NODES * HDIM * 2;                  // 32 MB
    unsigned short* h0b    = (unsigned short*)p;  p += nb;
    unsigned short* msgb   = (unsigned short*)p;  p += nb;
    unsigned short* h0p    = (unsigned short*)p;  p += nb;
    float*          gsum   = (float*)p;           p += (size_t)NGRAPH * HDIM * 4;
    float*          s2g    = (float*)p;           p += (size_t)NGRAPH * 64 * 4;
    unsigned short* wfrag  = (unsigned short*)p;  p += 32 * 64 * 16;
    unsigned short* winfrag= (unsigned short*)p;  p += 8 * 64 * 16;
    int*            count  = (int*)p;             p += (size_t)NODES * 4;
    int*            offs   = (int*)p;             p += (size_t)NODES * 4;
    int*            cursor = (int*)p;             p += (size_t)NODES * 4;
    int2*           bucket = (int2*)p;            p += (size_t)EDGES * 8;
    int*            cnt    = (int*)p;             p += (size_t)NGRAPH * 4;
    int*            bsums  = (int*)p;             p += 256 * 4;

    hipMemsetAsync(count, 0, (size_t)NODES * 4, stream);

    kprep   <<<14, 256, 0, stream>>>(Wmsg, Win, wfrag, winfrag, batch, cnt, gsum);
    k1_mfma <<<5120, 256, 0, stream>>>(x, winfrag, h0b, h0p, ei, count);
    kh_scanA<<<256, 256, 0, stream>>>(count, offs, bsums);
    kh_scanC<<<256, 256, 0, stream>>>(offs, cursor, bsums);
    kh_fill <<<EDGES / 256, 256, 0, stream>>>(ei, ew, cursor, bucket, EDGES);

    kg_gather<<<(NODES * 64) / 256, 256, 0, stream>>>(h0b, offs, cursor, bucket, msgb, NODES);

    k3a_mfma_pool<<<NODES / 128, 256, 0, stream>>>(msgb, h0p, wfrag, batch, gsum);

    k4a_backbone<<<NGRAPH, 128, 0, stream>>>(gsum, cnt, W1, W2, Wv1, Wv2, s2g, out);
    k4b_logits  <<<256, 256, 0, stream>>>(s2g, Wa, Ws, Wt, Wact, out);
}

// Round 9
// 184.227 us; speedup vs baseline: 1.7795x; 1.3514x over previous
//
#include <hip/hip_runtime.h>
#include <math.h>

#define NODES   131072
#define EDGES   1048576
#define FDIM    32
#define HDIM    128
#define NGRAPH  512

#define NB      64          // coarse buckets
#define BSH     11          // tgt>>11 -> bucket; 2048 nodes per bucket
#define MAXPER  20480       // slots per coarse bucket in scratch (avg 16384, +25%)
#define EPB     4096        // edges per kp1 block

typedef __attribute__((ext_vector_type(8))) short short8v;
typedef __attribute__((ext_vector_type(4))) float float4v;

__device__ __forceinline__ unsigned short f2bf(float f) {
    union { float f; unsigned int u; } v; v.f = f;
    unsigned int u = v.u;
    unsigned int r = (u + 0x7fffu + ((u >> 16) & 1u)) >> 16;   // RNE
    return (unsigned short)r;
}
__device__ __forceinline__ float bf2f(unsigned short u) {
    union { unsigned int u; float f; } v; v.u = ((unsigned int)u) << 16; return v.f;
}

// ---------------------------------------------------------------- k1: MFMA projection (pure)
__global__ __launch_bounds__(256) void k1_mfma(const float* __restrict__ x,
                                               const unsigned short* __restrict__ winfrag,
                                               unsigned short* __restrict__ h0b,
                                               unsigned short* __restrict__ h0p) {
    int b = blockIdx.x, t = threadIdx.x;
    int wid = t >> 6, l = t & 63;
    int base = b * 128;

    const short8v* wf8 = (const short8v*)winfrag;
    short8v wfr[8];
#pragma unroll
    for (int c = 0; c < 8; ++c) wfr[c] = wf8[c * 64 + l];

#pragma unroll
    for (int s = 0; s < 2; ++s) {
        int strip = base + wid * 32 + s * 16;
        int row = strip + (l & 15);
        const float* xr = x + (size_t)row * FDIM + (l >> 4) * 8;
        float4 x0 = ((const float4*)xr)[0];
        float4 x1 = ((const float4*)xr)[1];
        short8v af;
        af[0] = (short)f2bf(x0.x); af[1] = (short)f2bf(x0.y);
        af[2] = (short)f2bf(x0.z); af[3] = (short)f2bf(x0.w);
        af[4] = (short)f2bf(x1.x); af[5] = (short)f2bf(x1.y);
        af[6] = (short)f2bf(x1.z); af[7] = (short)f2bf(x1.w);

        float4v acc[8];
#pragma unroll
        for (int c = 0; c < 8; ++c) acc[c] = (float4v){0.f, 0.f, 0.f, 0.f};
#pragma unroll
        for (int c = 0; c < 8; ++c)
            acc[c] = __builtin_amdgcn_mfma_f32_16x16x32_bf16(af, wfr[c], acc[c], 0, 0, 0);

        int rbase = strip + (l >> 4) * 4;   // C/D: col = lane&15, row = (lane>>4)*4 + reg
        int col = l & 15;
#pragma unroll
        for (int r = 0; r < 4; ++r)
#pragma unroll
            for (int c = 0; c < 8; ++c)
                h0b[(size_t)(rbase + r) * HDIM + c * 16 + col] = f2bf(acc[c][r]);
        short8v* pp = (short8v*)(h0p + (size_t)strip * HDIM + l * 32);
#pragma unroll
        for (int r = 0; r < 4; ++r) {
            short8v v;
#pragma unroll
            for (int c = 0; c < 8; ++c) v[c] = (short)f2bf(acc[c][r]);
            pp[r] = v;
        }
    }
}

// ---------------------------------------------------------------- kp1: coarse partition (coalesced runs)
__global__ __launch_bounds__(256) void kp1_partition(const int* __restrict__ ei,
                                                     const float* __restrict__ ew,
                                                     int* __restrict__ coarse_cursor,
                                                     uint2* __restrict__ scratch) {
    __shared__ int hist[NB];
    __shared__ int excl[NB];
    __shared__ int gb[NB];
    __shared__ __align__(16) uint2 recL[EPB];     // 32KB
    __shared__ unsigned char bidL[EPB];           // 4KB

    int t = threadIdx.x;
    int e0 = blockIdx.x * EPB;

    if (t < NB) hist[t] = 0;
    __syncthreads();

    unsigned int rx[16]; unsigned int rw[16];
    int bb[16]; int lr[16];
#pragma unroll
    for (int i = 0; i < 16; ++i) {
        int e = e0 + t + 256 * i;
        int src = ei[e];
        int tgt = ei[EDGES + e];
        float w = ew[e];
        int bk = tgt >> BSH;
        rx[i] = (unsigned int)src | ((unsigned int)(tgt & ((1 << BSH) - 1)) << 17);
        rw[i] = __float_as_uint(w);
        bb[i] = bk;
        lr[i] = atomicAdd(&hist[bk], 1);
    }
    __syncthreads();

    if (t == 0) {
        int s = 0;
#pragma unroll
        for (int k = 0; k < NB; ++k) { excl[k] = s; s += hist[k]; }
    }
    __syncthreads();
    if (t < NB) gb[t] = atomicAdd(&coarse_cursor[t], hist[t]);
    __syncthreads();

#pragma unroll
    for (int i = 0; i < 16; ++i) {
        int pos = excl[bb[i]] + lr[i];
        recL[pos] = make_uint2(rx[i], rw[i]);
        bidL[pos] = (unsigned char)bb[i];
    }
    __syncthreads();

#pragma unroll
    for (int i = 0; i < 16; ++i) {
        int p = t + 256 * i;
        int bk = bidL[p];
        int dst = bk * MAXPER + gb[bk] + (p - excl[bk]);
        scratch[dst] = recL[p];
    }
}

// ---------------------------------------------------------------- kp2: fine CSR within coarse bucket
__global__ __launch_bounds__(256) void kp2_fine(const uint2* __restrict__ scratch,
                                                const int* __restrict__ coarse_cursor,
                                                int2* __restrict__ nbe,
                                                int2* __restrict__ csre) {
    __shared__ int fh[2048];      // fine hist -> cursor
    __shared__ int ts[256];
    __shared__ int cc[NB];
    __shared__ int cpre[NB];

    int b = blockIdx.x, t = threadIdx.x;

    if (t < NB) cc[t] = coarse_cursor[t];
    for (int i = t; i < 2048; i += 256) fh[i] = 0;
    __syncthreads();
    if (t == 0) {
        int s = 0;
#pragma unroll
        for (int k = 0; k < NB; ++k) { cpre[k] = s; s += cc[k]; }
    }
    __syncthreads();

    int cnt_b = cc[b];
    int gbase = cpre[b];
    const uint2* src = scratch + (size_t)b * MAXPER;

    for (int j = t; j < cnt_b; j += 256) {
        uint2 r = src[j];
        atomicAdd(&fh[r.x >> 17], 1);
    }
    __syncthreads();

    // block scan over 2048 counts
    int loc[8]; int s = 0;
#pragma unroll
    for (int q = 0; q < 8; ++q) { loc[q] = s; s += fh[t * 8 + q]; }
    ts[t] = s;
    __syncthreads();
    for (int off = 1; off < 256; off <<= 1) {
        int v = (t >= off) ? ts[t - off] : 0;
        __syncthreads();
        ts[t] += v;
        __syncthreads();
    }
    int tbase = ts[t] - s;

    // per-node {beg,end}, coalesced
#pragma unroll
    for (int q = 0; q < 8; ++q) {
        int nl = t * 8 + q;
        int cntn = fh[nl];
        int beg = gbase + tbase + loc[q];
        nbe[b * 2048 + nl] = make_int2(beg, beg + cntn);
    }
    __syncthreads();
#pragma unroll
    for (int q = 0; q < 8; ++q) fh[t * 8 + q] = gbase + tbase + loc[q];
    __syncthreads();

    // scatter into the bucket's contiguous 128KB window (L2-local)
    for (int j = t; j < cnt_b; j += 256) {
        uint2 r = src[j];
        int pos = atomicAdd(&fh[r.x >> 17], 1);
        csre[pos] = make_int2((int)(r.x & 0x1FFFFu), (int)r.y);
    }
}

// ---------------------------------------------------------------- prep: wfrag | winfrag | cnt | gsum-zero | cc-zero
__global__ __launch_bounds__(256) void kprep(const float* __restrict__ Wmsg,
                                             const float* __restrict__ Win,
                                             unsigned short* __restrict__ wfrag,
                                             unsigned short* __restrict__ winfrag,
                                             const int* __restrict__ batch,
                                             int* __restrict__ cnt,
                                             float* __restrict__ gsum,
                                             int* __restrict__ coarse_cursor) {
    int b = blockIdx.x, t = threadIdx.x;
    if (b < 8) {
        int flat = b * 256 + t;
        int l = flat & 63;
        int fragid = flat >> 6;
        int c = fragid >> 2, kk = fragid & 3;
        int col = c * 16 + (l & 15);
        int k0 = kk * 32 + (l >> 4) * 8;
        short8v v;
#pragma unroll
        for (int j = 0; j < 8; ++j)
            v[j] = (short)f2bf(Wmsg[(k0 + j) * HDIM + col]);
        ((short8v*)wfrag)[flat] = v;
    } else if (b < 10) {
        int flat = (b - 8) * 256 + t;
        int l = flat & 63;
        int c = flat >> 6;
        int col = c * 16 + (l & 15);
        int k0 = (l >> 4) * 8;
        short8v v;
#pragma unroll
        for (int j = 0; j < 8; ++j)
            v[j] = (short)f2bf(Win[(k0 + j) * HDIM + col]);
        ((short8v*)winfrag)[flat] = v;
    } else if (b < 12) {
        int g = (b - 10) * 256 + t;
        if (g < NGRAPH) {
            int lo = 0, hi = NODES;
            while (lo < hi) { int m = (lo + hi) >> 1; if (batch[m] < g) lo = m + 1; else hi = m; }
            int start = lo;
            hi = NODES;
            while (lo < hi) { int m = (lo + hi) >> 1; if (batch[m] < g + 1) lo = m + 1; else hi = m; }
            cnt[g] = lo - start;
        }
    } else if (b < 14) {
        float4* gz = (float4*)gsum;
        int idx = (b - 12) * 256 + t;
        for (int i = idx; i < 16384; i += 512) gz[i] = make_float4(0.f, 0.f, 0.f, 0.f);
    } else {
        if (t < NB) coarse_cursor[t] = 0;
    }
}

// ---------------------------------------------------------------- gather
__global__ __launch_bounds__(256) void kg_gather(const unsigned short* __restrict__ h0b,
                                                 const int2* __restrict__ nbe,
                                                 const int2* __restrict__ csre,
                                                 unsigned short* __restrict__ msgb, int N) {
    long long gid = blockIdx.x * (long long)blockDim.x + threadIdx.x;
    int n = (int)(gid >> 6);
    if (n >= N) return;
    int l = (int)(gid & 63);
    int2 be = nbe[n];
    int j = be.x, end = be.y;
    float ax = 0.f, ay = 0.f;
    for (; j + 4 <= end; j += 4) {
        int2 e0 = csre[j], e1 = csre[j + 1], e2 = csre[j + 2], e3 = csre[j + 3];
        unsigned int u0 = ((const unsigned int*)(h0b + (size_t)e0.x * HDIM))[l];
        unsigned int u1 = ((const unsigned int*)(h0b + (size_t)e1.x * HDIM))[l];
        unsigned int u2 = ((const unsigned int*)(h0b + (size_t)e2.x * HDIM))[l];
        unsigned int u3 = ((const unsigned int*)(h0b + (size_t)e3.x * HDIM))[l];
        float w0 = __int_as_float(e0.y), w1 = __int_as_float(e1.y);
        float w2 = __int_as_float(e2.y), w3 = __int_as_float(e3.y);
        ax = fmaf(__uint_as_float(u0 << 16), w0, ax); ay = fmaf(__uint_as_float(u0 & 0xFFFF0000u), w0, ay);
        ax = fmaf(__uint_as_float(u1 << 16), w1, ax); ay = fmaf(__uint_as_float(u1 & 0xFFFF0000u), w1, ay);
        ax = fmaf(__uint_as_float(u2 << 16), w2, ax); ay = fmaf(__uint_as_float(u2 & 0xFFFF0000u), w2, ay);
        ax = fmaf(__uint_as_float(u3 << 16), w3, ax); ay = fmaf(__uint_as_float(u3 & 0xFFFF0000u), w3, ay);
    }
    for (; j < end; ++j) {
        int2 e0 = csre[j];
        unsigned int u0 = ((const unsigned int*)(h0b + (size_t)e0.x * HDIM))[l];
        float w0 = __int_as_float(e0.y);
        ax = fmaf(__uint_as_float(u0 << 16), w0, ax); ay = fmaf(__uint_as_float(u0 & 0xFFFF0000u), w0, ay);
    }
    ushort2 o; o.x = f2bf(ax); o.y = f2bf(ay);
    ((ushort2*)(msgb + (size_t)n * HDIM))[l] = o;
}

// ---------------------------------------------------------------- k3a: MFMA GEMM + relu + pool (round-8 fast path)
__global__ __launch_bounds__(256) void k3a_mfma_pool(const unsigned short* __restrict__ msgb,
                                                     const unsigned short* __restrict__ h0p,
                                                     const unsigned short* __restrict__ wfrag,
                                                     const int* __restrict__ batch,
                                                     float* __restrict__ gsum) {
    __shared__ __align__(16) unsigned short blds[32 * 64 * 8];  // 32KB
    __shared__ float pool[8][HDIM];                              // 4KB
    __shared__ int batch_lds[128];

    int t = threadIdx.x;
    int wid = t >> 6, l = t & 63;
    int base = blockIdx.x * 128;

    {
        const uint4* sp = (const uint4*)wfrag;
        uint4* d = (uint4*)blds;
#pragma unroll
        for (int i = 0; i < 8; ++i) d[t + 256 * i] = sp[t + 256 * i];
    }
    if (t < 128) batch_lds[t] = batch[base + t];
    __syncthreads();

    int bfirst = batch_lds[0];
    int blast  = batch_lds[127];
    int span = blast - bfirst + 1;

    const short8v* Bl = (const short8v*)blds;
    int col = l & 15;

    if (span <= 2) {
        float pa[8], pb[8];
#pragma unroll
        for (int c = 0; c < 8; ++c) { pa[c] = 0.f; pb[c] = 0.f; }

#pragma unroll
        for (int s = 0; s < 2; ++s) {
            int strip = base + wid * 32 + s * 16;
            const short8v* mrow = (const short8v*)(msgb + (size_t)(strip + col) * HDIM);
            short8v af[4];
#pragma unroll
            for (int kk = 0; kk < 4; ++kk) af[kk] = mrow[kk * 4 + (l >> 4)];
            const short8v* hp = (const short8v*)(h0p + (size_t)strip * HDIM + l * 32);
            short8v h0r[4];
#pragma unroll
            for (int r = 0; r < 4; ++r) h0r[r] = hp[r];

            float4v acc[8];
#pragma unroll
            for (int c = 0; c < 8; ++c) acc[c] = (float4v){0.f, 0.f, 0.f, 0.f};
#pragma unroll
            for (int kk = 0; kk < 4; ++kk)
#pragma unroll
                for (int c = 0; c < 8; ++c)
                    acc[c] = __builtin_amdgcn_mfma_f32_16x16x32_bf16(af[kk], Bl[(c * 4 + kk) * 64 + l], acc[c], 0, 0, 0);

            int rbase = strip + (l >> 4) * 4;
#pragma unroll
            for (int r = 0; r < 4; ++r) {
                bool isA = (batch_lds[rbase + r - base] == bfirst);
#pragma unroll
                for (int c = 0; c < 8; ++c) {
                    float hv = fmaxf(bf2f((unsigned short)h0r[r][c]) + acc[c][r], 0.f);
                    pa[c] += isA ? hv : 0.f;
                    pb[c] += isA ? 0.f : hv;
                }
            }
        }
#pragma unroll
        for (int c = 0; c < 8; ++c) {
            pa[c] += __shfl_xor(pa[c], 16);
            pa[c] += __shfl_xor(pa[c], 32);
            pb[c] += __shfl_xor(pb[c], 16);
            pb[c] += __shfl_xor(pb[c], 32);
        }
        float (*p2)[2][HDIM] = (float (*)[2][HDIM])pool;
        if (l < 16) {
#pragma unroll
            for (int c = 0; c < 8; ++c) {
                p2[wid][0][c * 16 + l] = pa[c];
                p2[wid][1][c * 16 + l] = pb[c];
            }
        }
        __syncthreads();
        int cc2 = t & 127, sidx = t >> 7;
        if (sidx < span) {
            float v = p2[0][sidx][cc2] + p2[1][sidx][cc2] + p2[2][sidx][cc2] + p2[3][sidx][cc2];
            atomicAdd(&gsum[(size_t)(bfirst + sidx) * HDIM + cc2], v);
        }
    } else {
        bool lds_pool = (span <= 8);
        if (lds_pool) {
            float* pf = (float*)pool;
            for (int i = t; i < 8 * HDIM; i += 256) pf[i] = 0.f;
        }
        __syncthreads();

        int rsub = (l >> 4) * 4;
#pragma unroll
        for (int s = 0; s < 2; ++s) {
            int strip = base + wid * 32 + s * 16;
            const short8v* mrow = (const short8v*)(msgb + (size_t)(strip + col) * HDIM);
            short8v af[4];
#pragma unroll
            for (int kk = 0; kk < 4; ++kk) af[kk] = mrow[kk * 4 + (l >> 4)];
            const short8v* hp = (const short8v*)(h0p + (size_t)strip * HDIM + l * 32);
            short8v h0r[4];
#pragma unroll
            for (int r = 0; r < 4; ++r) h0r[r] = hp[r];

            float4v acc[8];
#pragma unroll
            for (int c = 0; c < 8; ++c) acc[c] = (float4v){0.f, 0.f, 0.f, 0.f};
#pragma unroll
            for (int kk = 0; kk < 4; ++kk)
#pragma unroll
                for (int c = 0; c < 8; ++c)
                    acc[c] = __builtin_amdgcn_mfma_f32_16x16x32_bf16(af[kk], Bl[(c * 4 + kk) * 64 + l], acc[c], 0, 0, 0);

            int rbase = strip + rsub;
            if (lds_pool) {
#pragma unroll
                for (int r = 0; r < 4; ++r) {
                    int g = batch_lds[rbase + r - base] - bfirst;
#pragma unroll
                    for (int c = 0; c < 8; ++c) {
                        float hv = fmaxf(bf2f((unsigned short)h0r[r][c]) + acc[c][r], 0.f);
                        atomicAdd(&pool[g][c * 16 + col], hv);
                    }
                }
            } else {
#pragma unroll
                for (int r = 0; r < 4; ++r) {
                    int g = batch_lds[rbase + r - base];
#pragma unroll
                    for (int c = 0; c < 8; ++c) {
                        float hv = fmaxf(bf2f((unsigned short)h0r[r][c]) + acc[c][r], 0.f);
                        atomicAdd(&gsum[(size_t)g * HDIM + c * 16 + col], hv);
                    }
                }
            }
        }
        __syncthreads();
        if (lds_pool) {
            int cc2 = t & 127;
            for (int s2 = t >> 7; s2 < span; s2 += 2)
                atomicAdd(&gsum[(size_t)(bfirst + s2) * HDIM + cc2], pool[s2][cc2]);
        }
    }
}

// ---------------------------------------------------------------- k4a: backbone + value head; writes s2g
__global__ __launch_bounds__(128) void k4a_backbone(const float* __restrict__ gsum,
                                                    const int* __restrict__ cnt,
                                                    const float* __restrict__ W1,
                                                    const float* __restrict__ W2,
                                                    const float* __restrict__ Wv1,
                                                    const float* __restrict__ Wv2,
                                                    float* __restrict__ s2g,
                                                    float* __restrict__ out) {
    int g = blockIdx.x;
    int t = threadIdx.x;
    __shared__ float gv[HDIM];
    __shared__ float s1[HDIM];
    __shared__ float s2v[64];
    __shared__ float v1[32];

    {
        int c = cnt[g];
        gv[t] = (c > 0) ? gsum[(size_t)g * HDIM + t] / (float)c : 0.f;
    }
    __syncthreads();

    {
        float s = 0.f;
#pragma unroll 8
        for (int k = 0; k < HDIM; ++k)
            s = fmaf(gv[k], W1[k * HDIM + t] + W1[(k + HDIM) * HDIM + t], s);
        s1[t] = fmaxf(s, 0.f);
    }
    __syncthreads();

    if (t < 64) {
        float s = 0.f;
#pragma unroll 8
        for (int k = 0; k < HDIM; ++k)
            s = fmaf(s1[k], W2[k * 64 + t], s);
        float sv = fmaxf(s, 0.f);
        s2v[t] = sv;
        s2g[(size_t)g * 64 + t] = sv;
    }
    __syncthreads();

    if (t < 32) {
        float s = 0.f;
#pragma unroll 8
        for (int k = 0; k < 64; ++k)
            s = fmaf(s2v[k], Wv1[k * 32 + t], s);
        v1[t] = fmaxf(s, 0.f);
    }
    __syncthreads();
    if (t == 0) {
        float s = 0.f;
#pragma unroll
        for (int k = 0; k < 32; ++k)
            s = fmaf(v1[k], Wv2[k], s);
        out[1028608 + (size_t)g] = tanhf(s);
    }
}

// ---------------------------------------------------------------- k4b: logits GEMM [512,64]@[64,2009]
__global__ __launch_bounds__(256) void k4b_logits(const float* __restrict__ s2g,
                                                  const float* __restrict__ Wa,
                                                  const float* __restrict__ Ws,
                                                  const float* __restrict__ Wt,
                                                  const float* __restrict__ Wact,
                                                  float* __restrict__ out) {
    int ctile = blockIdx.x & 7;
    int gbase = (blockIdx.x >> 3) * 16;
    int t = threadIdx.x;
    int col = ctile * 256 + t;

    __shared__ float4 s2s4[16][16];
    {
        int g = t >> 4, q = t & 15;
        s2s4[g][q] = ((const float4*)(s2g + (size_t)(gbase + g) * 64))[q];
    }

    bool valid = (col < 2009);
    const float* W = Wa; int colc = 0, ncol = 5; size_t hb = 0;
    if (col < 5)        { W = Wa;   colc = col;        ncol = 5;    hb = 0; }
    else if (col < 1005){ W = Ws;   colc = col - 5;    ncol = 1000; hb = 2560; }
    else if (col < 2005){ W = Wt;   colc = col - 1005; ncol = 1000; hb = 514560; }
    else                { W = Wact; colc = col - 2005; ncol = 4;    hb = 1026560; }

    float wr[64];
#pragma unroll
    for (int k = 0; k < 64; ++k)
        wr[k] = valid ? W[(size_t)k * ncol + colc] : 0.f;
    __syncthreads();

    for (int gg = 0; gg < 16; ++gg) {
        const float4* s4 = (const float4*)s2s4[gg];
        float a = 0.f;
#pragma unroll
        for (int q = 0; q < 16; ++q) {
            float4 v = s4[q];
            a = fmaf(v.x, wr[4 * q + 0], a);
            a = fmaf(v.y, wr[4 * q + 1], a);
            a = fmaf(v.z, wr[4 * q + 2], a);
            a = fmaf(v.w, wr[4 * q + 3], a);
        }
        if (valid) out[hb + (size_t)(gbase + gg) * ncol + colc] = a;
    }
}

// ----------------------------------------------------------------
extern "C" void kernel_launch(void* const* d_in, const int* in_sizes, int n_in,
                              void* d_out, int out_size, void* d_ws, size_t ws_size,
                              hipStream_t stream) {
    const float* x     = (const float*)d_in[0];
    const int*   ei    = (const int*)d_in[1];
    const float* ew    = (const float*)d_in[2];
    const int*   batch = (const int*)d_in[4];
    const float* Win   = (const float*)d_in[6];
    const float* Wmsg  = (const float*)d_in[7];
    const float* W1    = (const float*)d_in[8];
    const float* W2    = (const float*)d_in[9];
    const float* Wa    = (const float*)d_in[10];
    const float* Ws    = (const float*)d_in[11];
    const float* Wt    = (const float*)d_in[12];
    const float* Wact  = (const float*)d_in[13];
    const float* Wv1   = (const float*)d_in[14];
    const float* Wv2   = (const float*)d_in[15];
    float* out = (float*)d_out;

    char* p = (char*)d_ws;
    const size_t nb = (size_t)NODES * HDIM * 2;                  // 32 MB
    unsigned short* h0b    = (unsigned short*)p;  p += nb;
    unsigned short* msgb   = (unsigned short*)p;  p += nb;
    unsigned short* h0p    = (unsigned short*)p;  p += nb;
    float*          gsum   = (float*)p;           p += (size_t)NGRAPH * HDIM * 4;
    float*          s2g    = (float*)p;           p += (size_t)NGRAPH * 64 * 4;
    unsigned short* wfrag  = (unsigned short*)p;  p += 32 * 64 * 16;
    unsigned short* winfrag= (unsigned short*)p;  p += 8 * 64 * 16;
    int*            cnt    = (int*)p;             p += (size_t)NGRAPH * 4;
    int*            ccur   = (int*)p;             p += 256;               // NB=64 + pad
    uint2*          scratch= (uint2*)p;           p += (size_t)NB * MAXPER * 8;   // 10.5 MB
    int2*           nbe    = (int2*)p;            p += (size_t)NODES * 8;         // 1 MB
    int2*           csre   = (int2*)p;            p += (size_t)EDGES * 8;         // 8 MB

    kprep        <<<15, 256, 0, stream>>>(Wmsg, Win, wfrag, winfrag, batch, cnt, gsum, ccur);
    k1_mfma      <<<1024, 256, 0, stream>>>(x, winfrag, h0b, h0p);
    kp1_partition<<<EDGES / EPB, 256, 0, stream>>>(ei, ew, ccur, scratch);
    kp2_fine     <<<NB, 256, 0, stream>>>(scratch, ccur, nbe, csre);

    kg_gather    <<<(NODES * 64) / 256, 256, 0, stream>>>(h0b, nbe, csre, msgb, NODES);

    k3a_mfma_pool<<<NODES / 128, 256, 0, stream>>>(msgb, h0p, wfrag, batch, gsum);

    k4a_backbone <<<NGRAPH, 128, 0, stream>>>(gsum, cnt, W1, W2, Wv1, Wv2, s2g, out);
    k4b_logits   <<<256, 256, 0, stream>>>(s2g, Wa, Ws, Wt, Wact, out);
}

// Round 10
// 177.803 us; speedup vs baseline: 1.8438x; 1.0361x over previous
//
#include <hip/hip_runtime.h>
#include <math.h>

#define NODES   131072
#define EDGES   1048576
#define FDIM    32
#define HDIM    128
#define NGRAPH  512

#define NB      64          // coarse buckets
#define BSH     11          // tgt>>11 -> bucket; 2048 nodes per bucket
#define MAXPER  20480       // slots per coarse bucket in scratch
#define EPB     4096        // edges per kp1 block

typedef __attribute__((ext_vector_type(8))) short short8v;
typedef __attribute__((ext_vector_type(4))) float float4v;
typedef __attribute__((ext_vector_type(2))) float float2v;

__device__ __forceinline__ unsigned short f2bf(float f) {
    union { float f; unsigned int u; } v; v.f = f;
    unsigned int u = v.u;
    unsigned int r = (u + 0x7fffu + ((u >> 16) & 1u)) >> 16;   // RNE
    return (unsigned short)r;
}
__device__ __forceinline__ float bf2f(unsigned short u) {
    union { unsigned int u; float f; } v; v.u = ((unsigned int)u) << 16; return v.f;
}

// ---------------------------------------------------------------- k1: MFMA projection
// Outputs: h0f8 (fp8 e4m3, POSITION-space rows: pos p holds true col k(p)=(p&7)*16+(p>>3))
//          h0p  (bf16 C/D-frag-permuted copy for k3a epilogue)
__global__ __launch_bounds__(256) void k1_mfma(const float* __restrict__ x,
                                               const unsigned short* __restrict__ winfrag,
                                               unsigned char* __restrict__ h0f8,
                                               unsigned short* __restrict__ h0p) {
    int b = blockIdx.x, t = threadIdx.x;
    int wid = t >> 6, l = t & 63;
    int base = b * 128;

    const short8v* wf8 = (const short8v*)winfrag;
    short8v wfr[8];
#pragma unroll
    for (int c = 0; c < 8; ++c) wfr[c] = wf8[c * 64 + l];

#pragma unroll
    for (int s = 0; s < 2; ++s) {
        int strip = base + wid * 32 + s * 16;
        int row = strip + (l & 15);
        const float* xr = x + (size_t)row * FDIM + (l >> 4) * 8;
        float4 x0 = ((const float4*)xr)[0];
        float4 x1 = ((const float4*)xr)[1];
        short8v af;
        af[0] = (short)f2bf(x0.x); af[1] = (short)f2bf(x0.y);
        af[2] = (short)f2bf(x0.z); af[3] = (short)f2bf(x0.w);
        af[4] = (short)f2bf(x1.x); af[5] = (short)f2bf(x1.y);
        af[6] = (short)f2bf(x1.z); af[7] = (short)f2bf(x1.w);

        float4v acc[8];
#pragma unroll
        for (int c = 0; c < 8; ++c) acc[c] = (float4v){0.f, 0.f, 0.f, 0.f};
#pragma unroll
        for (int c = 0; c < 8; ++c)
            acc[c] = __builtin_amdgcn_mfma_f32_16x16x32_bf16(af, wfr[c], acc[c], 0, 0, 0);

        int rbase = strip + (l >> 4) * 4;   // C/D: col = lane&15, row = (lane>>4)*4 + reg
        int m = l & 15;
        // fp8 gather copy: lane writes positions [m*8, m*8+8) of rows rbase..rbase+3 (8B/row)
#pragma unroll
        for (int r = 0; r < 4; ++r) {
            int w0 = __builtin_amdgcn_cvt_pk_fp8_f32(acc[0][r], acc[1][r], 0, false);
            w0     = __builtin_amdgcn_cvt_pk_fp8_f32(acc[2][r], acc[3][r], w0, true);
            int w1 = __builtin_amdgcn_cvt_pk_fp8_f32(acc[4][r], acc[5][r], 0, false);
            w1     = __builtin_amdgcn_cvt_pk_fp8_f32(acc[6][r], acc[7][r], w1, true);
            *((uint2*)(h0f8 + (size_t)(rbase + r) * HDIM + m * 8)) = make_uint2((unsigned)w0, (unsigned)w1);
        }
        // bf16 C/D-frag copy for k3a epilogue (true-col order, as before)
        short8v* pp = (short8v*)(h0p + (size_t)strip * HDIM + l * 32);
#pragma unroll
        for (int r = 0; r < 4; ++r) {
            short8v v;
#pragma unroll
            for (int c = 0; c < 8; ++c) v[c] = (short)f2bf(acc[c][r]);
            pp[r] = v;
        }
    }
}

// ---------------------------------------------------------------- kp1: coarse partition
__global__ __launch_bounds__(256) void kp1_partition(const int* __restrict__ ei,
                                                     const float* __restrict__ ew,
                                                     int* __restrict__ coarse_cursor,
                                                     uint2* __restrict__ scratch) {
    __shared__ int hist[NB];
    __shared__ int excl[NB];
    __shared__ int gb[NB];
    __shared__ __align__(16) uint2 recL[EPB];
    __shared__ unsigned char bidL[EPB];

    int t = threadIdx.x;
    int e0 = blockIdx.x * EPB;

    if (t < NB) hist[t] = 0;
    __syncthreads();

    unsigned int rx[16]; unsigned int rw[16];
    int bb[16]; int lr[16];
#pragma unroll
    for (int i = 0; i < 16; ++i) {
        int e = e0 + t + 256 * i;
        int src = ei[e];
        int tgt = ei[EDGES + e];
        float w = ew[e];
        int bk = tgt >> BSH;
        rx[i] = (unsigned int)src | ((unsigned int)(tgt & ((1 << BSH) - 1)) << 17);
        rw[i] = __float_as_uint(w);
        bb[i] = bk;
        lr[i] = atomicAdd(&hist[bk], 1);
    }
    __syncthreads();

    if (t == 0) {
        int s = 0;
#pragma unroll
        for (int k = 0; k < NB; ++k) { excl[k] = s; s += hist[k]; }
    }
    __syncthreads();
    if (t < NB) gb[t] = atomicAdd(&coarse_cursor[t], hist[t]);
    __syncthreads();

#pragma unroll
    for (int i = 0; i < 16; ++i) {
        int pos = excl[bb[i]] + lr[i];
        recL[pos] = make_uint2(rx[i], rw[i]);
        bidL[pos] = (unsigned char)bb[i];
    }
    __syncthreads();

#pragma unroll
    for (int i = 0; i < 16; ++i) {
        int p = t + 256 * i;
        int bk = bidL[p];
        int dst = bk * MAXPER + gb[bk] + (p - excl[bk]);
        scratch[dst] = recL[p];
    }
}

// ---------------------------------------------------------------- kp2: fine CSR within coarse bucket
__global__ __launch_bounds__(256) void kp2_fine(const uint2* __restrict__ scratch,
                                                const int* __restrict__ coarse_cursor,
                                                int2* __restrict__ nbe,
                                                int2* __restrict__ csre) {
    __shared__ int fh[2048];
    __shared__ int ts[256];
    __shared__ int cc[NB];
    __shared__ int cpre[NB];

    int b = blockIdx.x, t = threadIdx.x;

    if (t < NB) cc[t] = coarse_cursor[t];
    for (int i = t; i < 2048; i += 256) fh[i] = 0;
    __syncthreads();
    if (t == 0) {
        int s = 0;
#pragma unroll
        for (int k = 0; k < NB; ++k) { cpre[k] = s; s += cc[k]; }
    }
    __syncthreads();

    int cnt_b = cc[b];
    int gbase = cpre[b];
    const uint2* src = scratch + (size_t)b * MAXPER;

    for (int j = t; j < cnt_b; j += 256) {
        uint2 r = src[j];
        atomicAdd(&fh[r.x >> 17], 1);
    }
    __syncthreads();

    int loc[8]; int s = 0;
#pragma unroll
    for (int q = 0; q < 8; ++q) { loc[q] = s; s += fh[t * 8 + q]; }
    ts[t] = s;
    __syncthreads();
    for (int off = 1; off < 256; off <<= 1) {
        int v = (t >= off) ? ts[t - off] : 0;
        __syncthreads();
        ts[t] += v;
        __syncthreads();
    }
    int tbase = ts[t] - s;

#pragma unroll
    for (int q = 0; q < 8; ++q) {
        int nl = t * 8 + q;
        int cntn = fh[nl];
        int beg = gbase + tbase + loc[q];
        nbe[b * 2048 + nl] = make_int2(beg, beg + cntn);
    }
    __syncthreads();
#pragma unroll
    for (int q = 0; q < 8; ++q) fh[t * 8 + q] = gbase + tbase + loc[q];
    __syncthreads();

    for (int j = t; j < cnt_b; j += 256) {
        uint2 r = src[j];
        int pos = atomicAdd(&fh[r.x >> 17], 1);
        csre[pos] = make_int2((int)(r.x & 0x1FFFFu), (int)r.y);
    }
}

// ---------------------------------------------------------------- prep: wfrag (k-rows in POSITION order) | winfrag | cnt | gsum-zero | cc-zero
__global__ __launch_bounds__(256) void kprep(const float* __restrict__ Wmsg,
                                             const float* __restrict__ Win,
                                             unsigned short* __restrict__ wfrag,
                                             unsigned short* __restrict__ winfrag,
                                             const int* __restrict__ batch,
                                             int* __restrict__ cnt,
                                             float* __restrict__ gsum,
                                             int* __restrict__ coarse_cursor) {
    int b = blockIdx.x, t = threadIdx.x;
    if (b < 8) {
        int flat = b * 256 + t;
        int l = flat & 63;
        int fragid = flat >> 6;
        int c = fragid >> 2, kk = fragid & 3;
        int col = c * 16 + (l & 15);
        short8v v;
#pragma unroll
        for (int j = 0; j < 8; ++j) {
            int q = kk * 32 + (l >> 4) * 8 + j;          // position-space k
            int krow = (q & 7) * 16 + (q >> 3);          // true k = kappa(q)
            v[j] = (short)f2bf(Wmsg[krow * HDIM + col]);
        }
        ((short8v*)wfrag)[flat] = v;
    } else if (b < 10) {
        int flat = (b - 8) * 256 + t;
        int l = flat & 63;
        int c = flat >> 6;
        int col = c * 16 + (l & 15);
        int k0 = (l >> 4) * 8;
        short8v v;
#pragma unroll
        for (int j = 0; j < 8; ++j)
            v[j] = (short)f2bf(Win[(k0 + j) * HDIM + col]);
        ((short8v*)winfrag)[flat] = v;
    } else if (b < 12) {
        int g = (b - 10) * 256 + t;
        if (g < NGRAPH) {
            int lo = 0, hi = NODES;
            while (lo < hi) { int m = (lo + hi) >> 1; if (batch[m] < g) lo = m + 1; else hi = m; }
            int start = lo;
            hi = NODES;
            while (lo < hi) { int m = (lo + hi) >> 1; if (batch[m] < g + 1) lo = m + 1; else hi = m; }
            cnt[g] = lo - start;
        }
    } else if (b < 14) {
        float4* gz = (float4*)gsum;
        int idx = (b - 12) * 256 + t;
        for (int i = idx; i < 16384; i += 512) gz[i] = make_float4(0.f, 0.f, 0.f, 0.f);
    } else {
        if (t < NB) coarse_cursor[t] = 0;
    }
}

// ---------------------------------------------------------------- gather (fp8 rows, position-space)
// lane l accumulates positions 2l,2l+1; msgb written in position space (= k3a's A-frag layout)
__global__ __launch_bounds__(256) void kg_gather(const unsigned char* __restrict__ h0f8,
                                                 const int2* __restrict__ nbe,
                                                 const int2* __restrict__ csre,
                                                 unsigned short* __restrict__ msgb, int N) {
    long long gid = blockIdx.x * (long long)blockDim.x + threadIdx.x;
    int n = (int)(gid >> 6);
    if (n >= N) return;
    int l = (int)(gid & 63);
    int2 be = nbe[n];
    int j = be.x, end = be.y;
    float ax = 0.f, ay = 0.f;
    for (; j + 4 <= end; j += 4) {
        int2 e0 = csre[j], e1 = csre[j + 1], e2 = csre[j + 2], e3 = csre[j + 3];
        unsigned short u0 = ((const unsigned short*)(h0f8 + (size_t)e0.x * HDIM))[l];
        unsigned short u1 = ((const unsigned short*)(h0f8 + (size_t)e1.x * HDIM))[l];
        unsigned short u2 = ((const unsigned short*)(h0f8 + (size_t)e2.x * HDIM))[l];
        unsigned short u3 = ((const unsigned short*)(h0f8 + (size_t)e3.x * HDIM))[l];
        float w0 = __int_as_float(e0.y), w1 = __int_as_float(e1.y);
        float w2 = __int_as_float(e2.y), w3 = __int_as_float(e3.y);
        float2v v0 = __builtin_amdgcn_cvt_pk_f32_fp8((int)u0, false);
        float2v v1 = __builtin_amdgcn_cvt_pk_f32_fp8((int)u1, false);
        float2v v2 = __builtin_amdgcn_cvt_pk_f32_fp8((int)u2, false);
        float2v v3 = __builtin_amdgcn_cvt_pk_f32_fp8((int)u3, false);
        ax = fmaf(v0.x, w0, ax); ay = fmaf(v0.y, w0, ay);
        ax = fmaf(v1.x, w1, ax); ay = fmaf(v1.y, w1, ay);
        ax = fmaf(v2.x, w2, ax); ay = fmaf(v2.y, w2, ay);
        ax = fmaf(v3.x, w3, ax); ay = fmaf(v3.y, w3, ay);
    }
    for (; j < end; ++j) {
        int2 e0 = csre[j];
        unsigned short u0 = ((const unsigned short*)(h0f8 + (size_t)e0.x * HDIM))[l];
        float w0 = __int_as_float(e0.y);
        float2v v0 = __builtin_amdgcn_cvt_pk_f32_fp8((int)u0, false);
        ax = fmaf(v0.x, w0, ax); ay = fmaf(v0.y, w0, ay);
    }
    ushort2 o; o.x = f2bf(ax); o.y = f2bf(ay);
    ((ushort2*)(msgb + (size_t)n * HDIM))[l] = o;
}

// ---------------------------------------------------------------- k3a: MFMA GEMM + relu + pool (unchanged from round 8/9)
__global__ __launch_bounds__(256) void k3a_mfma_pool(const unsigned short* __restrict__ msgb,
                                                     const unsigned short* __restrict__ h0p,
                                                     const unsigned short* __restrict__ wfrag,
                                                     const int* __restrict__ batch,
                                                     float* __restrict__ gsum) {
    __shared__ __align__(16) unsigned short blds[32 * 64 * 8];  // 32KB
    __shared__ float pool[8][HDIM];
    __shared__ int batch_lds[128];

    int t = threadIdx.x;
    int wid = t >> 6, l = t & 63;
    int base = blockIdx.x * 128;

    {
        const uint4* sp = (const uint4*)wfrag;
        uint4* d = (uint4*)blds;
#pragma unroll
        for (int i = 0; i < 8; ++i) d[t + 256 * i] = sp[t + 256 * i];
    }
    if (t < 128) batch_lds[t] = batch[base + t];
    __syncthreads();

    int bfirst = batch_lds[0];
    int blast  = batch_lds[127];
    int span = blast - bfirst + 1;

    const short8v* Bl = (const short8v*)blds;
    int col = l & 15;

    if (span <= 2) {
        float pa[8], pb[8];
#pragma unroll
        for (int c = 0; c < 8; ++c) { pa[c] = 0.f; pb[c] = 0.f; }

#pragma unroll
        for (int s = 0; s < 2; ++s) {
            int strip = base + wid * 32 + s * 16;
            const short8v* mrow = (const short8v*)(msgb + (size_t)(strip + col) * HDIM);
            short8v af[4];
#pragma unroll
            for (int kk = 0; kk < 4; ++kk) af[kk] = mrow[kk * 4 + (l >> 4)];
            const short8v* hp = (const short8v*)(h0p + (size_t)strip * HDIM + l * 32);
            short8v h0r[4];
#pragma unroll
            for (int r = 0; r < 4; ++r) h0r[r] = hp[r];

            float4v acc[8];
#pragma unroll
            for (int c = 0; c < 8; ++c) acc[c] = (float4v){0.f, 0.f, 0.f, 0.f};
#pragma unroll
            for (int kk = 0; kk < 4; ++kk)
#pragma unroll
                for (int c = 0; c < 8; ++c)
                    acc[c] = __builtin_amdgcn_mfma_f32_16x16x32_bf16(af[kk], Bl[(c * 4 + kk) * 64 + l], acc[c], 0, 0, 0);

            int rbase = strip + (l >> 4) * 4;
#pragma unroll
            for (int r = 0; r < 4; ++r) {
                bool isA = (batch_lds[rbase + r - base] == bfirst);
#pragma unroll
                for (int c = 0; c < 8; ++c) {
                    float hv = fmaxf(bf2f((unsigned short)h0r[r][c]) + acc[c][r], 0.f);
                    pa[c] += isA ? hv : 0.f;
                    pb[c] += isA ? 0.f : hv;
                }
            }
        }
#pragma unroll
        for (int c = 0; c < 8; ++c) {
            pa[c] += __shfl_xor(pa[c], 16);
            pa[c] += __shfl_xor(pa[c], 32);
            pb[c] += __shfl_xor(pb[c], 16);
            pb[c] += __shfl_xor(pb[c], 32);
        }
        float (*p2)[2][HDIM] = (float (*)[2][HDIM])pool;
        if (l < 16) {
#pragma unroll
            for (int c = 0; c < 8; ++c) {
                p2[wid][0][c * 16 + l] = pa[c];
                p2[wid][1][c * 16 + l] = pb[c];
            }
        }
        __syncthreads();
        int cc2 = t & 127, sidx = t >> 7;
        if (sidx < span) {
            float v = p2[0][sidx][cc2] + p2[1][sidx][cc2] + p2[2][sidx][cc2] + p2[3][sidx][cc2];
            atomicAdd(&gsum[(size_t)(bfirst + sidx) * HDIM + cc2], v);
        }
    } else {
        bool lds_pool = (span <= 8);
        if (lds_pool) {
            float* pf = (float*)pool;
            for (int i = t; i < 8 * HDIM; i += 256) pf[i] = 0.f;
        }
        __syncthreads();

        int rsub = (l >> 4) * 4;
#pragma unroll
        for (int s = 0; s < 2; ++s) {
            int strip = base + wid * 32 + s * 16;
            const short8v* mrow = (const short8v*)(msgb + (size_t)(strip + col) * HDIM);
            short8v af[4];
#pragma unroll
            for (int kk = 0; kk < 4; ++kk) af[kk] = mrow[kk * 4 + (l >> 4)];
            const short8v* hp = (const short8v*)(h0p + (size_t)strip * HDIM + l * 32);
            short8v h0r[4];
#pragma unroll
            for (int r = 0; r < 4; ++r) h0r[r] = hp[r];

            float4v acc[8];
#pragma unroll
            for (int c = 0; c < 8; ++c) acc[c] = (float4v){0.f, 0.f, 0.f, 0.f};
#pragma unroll
            for (int kk = 0; kk < 4; ++kk)
#pragma unroll
                for (int c = 0; c < 8; ++c)
                    acc[c] = __builtin_amdgcn_mfma_f32_16x16x32_bf16(af[kk], Bl[(c * 4 + kk) * 64 + l], acc[c], 0, 0, 0);

            int rbase = strip + rsub;
            if (lds_pool) {
#pragma unroll
                for (int r = 0; r < 4; ++r) {
                    int g = batch_lds[rbase + r - base] - bfirst;
#pragma unroll
                    for (int c = 0; c < 8; ++c) {
                        float hv = fmaxf(bf2f((unsigned short)h0r[r][c]) + acc[c][r], 0.f);
                        atomicAdd(&pool[g][c * 16 + col], hv);
                    }
                }
            } else {
#pragma unroll
                for (int r = 0; r < 4; ++r) {
                    int g = batch_lds[rbase + r - base];
#pragma unroll
                    for (int c = 0; c < 8; ++c) {
                        float hv = fmaxf(bf2f((unsigned short)h0r[r][c]) + acc[c][r], 0.f);
                        atomicAdd(&gsum[(size_t)g * HDIM + c * 16 + col], hv);
                    }
                }
            }
        }
        __syncthreads();
        if (lds_pool) {
            int cc2 = t & 127;
            for (int s2 = t >> 7; s2 < span; s2 += 2)
                atomicAdd(&gsum[(size_t)(bfirst + s2) * HDIM + cc2], pool[s2][cc2]);
        }
    }
}

// ---------------------------------------------------------------- k4a: backbone + value head
__global__ __launch_bounds__(128) void k4a_backbone(const float* __restrict__ gsum,
                                                    const int* __restrict__ cnt,
                                                    const float* __restrict__ W1,
                                                    const float* __restrict__ W2,
                                                    const float* __restrict__ Wv1,
                                                    const float* __restrict__ Wv2,
                                                    float* __restrict__ s2g,
                                                    float* __restrict__ out) {
    int g = blockIdx.x;
    int t = threadIdx.x;
    __shared__ float gv[HDIM];
    __shared__ float s1[HDIM];
    __shared__ float s2v[64];
    __shared__ float v1[32];

    {
        int c = cnt[g];
        gv[t] = (c > 0) ? gsum[(size_t)g * HDIM + t] / (float)c : 0.f;
    }
    __syncthreads();

    {
        float s = 0.f;
#pragma unroll 8
        for (int k = 0; k < HDIM; ++k)
            s = fmaf(gv[k], W1[k * HDIM + t] + W1[(k + HDIM) * HDIM + t], s);
        s1[t] = fmaxf(s, 0.f);
    }
    __syncthreads();

    if (t < 64) {
        float s = 0.f;
#pragma unroll 8
        for (int k = 0; k < HDIM; ++k)
            s = fmaf(s1[k], W2[k * 64 + t], s);
        float sv = fmaxf(s, 0.f);
        s2v[t] = sv;
        s2g[(size_t)g * 64 + t] = sv;
    }
    __syncthreads();

    if (t < 32) {
        float s = 0.f;
#pragma unroll 8
        for (int k = 0; k < 64; ++k)
            s = fmaf(s2v[k], Wv1[k * 32 + t], s);
        v1[t] = fmaxf(s, 0.f);
    }
    __syncthreads();
    if (t == 0) {
        float s = 0.f;
#pragma unroll
        for (int k = 0; k < 32; ++k)
            s = fmaf(v1[k], Wv2[k], s);
        out[1028608 + (size_t)g] = tanhf(s);
    }
}

// ---------------------------------------------------------------- k4b: logits GEMM [512,64]@[64,2009]
__global__ __launch_bounds__(256) void k4b_logits(const float* __restrict__ s2g,
                                                  const float* __restrict__ Wa,
                                                  const float* __restrict__ Ws,
                                                  const float* __restrict__ Wt,
                                                  const float* __restrict__ Wact,
                                                  float* __restrict__ out) {
    int ctile = blockIdx.x & 7;
    int gbase = (blockIdx.x >> 3) * 16;
    int t = threadIdx.x;
    int col = ctile * 256 + t;

    __shared__ float4 s2s4[16][16];
    {
        int g = t >> 4, q = t & 15;
        s2s4[g][q] = ((const float4*)(s2g + (size_t)(gbase + g) * 64))[q];
    }

    bool valid = (col < 2009);
    const float* W = Wa; int colc = 0, ncol = 5; size_t hb = 0;
    if (col < 5)        { W = Wa;   colc = col;        ncol = 5;    hb = 0; }
    else if (col < 1005){ W = Ws;   colc = col - 5;    ncol = 1000; hb = 2560; }
    else if (col < 2005){ W = Wt;   colc = col - 1005; ncol = 1000; hb = 514560; }
    else                { W = Wact; colc = col - 2005; ncol = 4;    hb = 1026560; }

    float wr[64];
#pragma unroll
    for (int k = 0; k < 64; ++k)
        wr[k] = valid ? W[(size_t)k * ncol + colc] : 0.f;
    __syncthreads();

    for (int gg = 0; gg < 16; ++gg) {
        const float4* s4 = (const float4*)s2s4[gg];
        float a = 0.f;
#pragma unroll
        for (int q = 0; q < 16; ++q) {
            float4 v = s4[q];
            a = fmaf(v.x, wr[4 * q + 0], a);
            a = fmaf(v.y, wr[4 * q + 1], a);
            a = fmaf(v.z, wr[4 * q + 2], a);
            a = fmaf(v.w, wr[4 * q + 3], a);
        }
        if (valid) out[hb + (size_t)(gbase + gg) * ncol + colc] = a;
    }
}

// ----------------------------------------------------------------
extern "C" void kernel_launch(void* const* d_in, const int* in_sizes, int n_in,
                              void* d_out, int out_size, void* d_ws, size_t ws_size,
                              hipStream_t stream) {
    const float* x     = (const float*)d_in[0];
    const int*   ei    = (const int*)d_in[1];
    const float* ew    = (const float*)d_in[2];
    const int*   batch = (const int*)d_in[4];
    const float* Win   = (const float*)d_in[6];
    const float* Wmsg  = (const float*)d_in[7];
    const float* W1    = (const float*)d_in[8];
    const float* W2    = (const float*)d_in[9];
    const float* Wa    = (const float*)d_in[10];
    const float* Ws    = (const float*)d_in[11];
    const float* Wt    = (const float*)d_in[12];
    const float* Wact  = (const float*)d_in[13];
    const float* Wv1   = (const float*)d_in[14];
    const float* Wv2   = (const float*)d_in[15];
    float* out = (float*)d_out;

    char* p = (char*)d_ws;
    const size_t nb = (size_t)NODES * HDIM * 2;                  // 32 MB
    unsigned char*  h0f8   = (unsigned char*)p;   p += (size_t)NODES * HDIM;   // 16 MB
    unsigned short* msgb   = (unsigned short*)p;  p += nb;
    unsigned short* h0p    = (unsigned short*)p;  p += nb;
    float*          gsum   = (float*)p;           p += (size_t)NGRAPH * HDIM * 4;
    float*          s2g    = (float*)p;           p += (size_t)NGRAPH * 64 * 4;
    unsigned short* wfrag  = (unsigned short*)p;  p += 32 * 64 * 16;
    unsigned short* winfrag= (unsigned short*)p;  p += 8 * 64 * 16;
    int*            cnt    = (int*)p;             p += (size_t)NGRAPH * 4;
    int*            ccur   = (int*)p;             p += 256;
    uint2*          scratch= (uint2*)p;           p += (size_t)NB * MAXPER * 8;
    int2*           nbe    = (int2*)p;            p += (size_t)NODES * 8;
    int2*           csre   = (int2*)p;            p += (size_t)EDGES * 8;

    kprep        <<<15, 256, 0, stream>>>(Wmsg, Win, wfrag, winfrag, batch, cnt, gsum, ccur);
    k1_mfma      <<<1024, 256, 0, stream>>>(x, winfrag, h0f8, h0p);
    kp1_partition<<<EDGES / EPB, 256, 0, stream>>>(ei, ew, ccur, scratch);
    kp2_fine     <<<NB, 256, 0, stream>>>(scratch, ccur, nbe, csre);

    kg_gather    <<<(NODES * 64) / 256, 256, 0, stream>>>(h0f8, nbe, csre, msgb, NODES);

    k3a_mfma_pool<<<NODES / 128, 256, 0, stream>>>(msgb, h0p, wfrag, batch, gsum);

    k4a_backbone <<<NGRAPH, 128, 0, stream>>>(gsum, cnt, W1, W2, Wv1, Wv2, s2g, out);
    k4b_logits   <<<256, 256, 0, stream>>>(s2g, Wa, Ws, Wt, Wact, out);
}

// Round 11
// 153.367 us; speedup vs baseline: 2.1376x; 1.1593x over previous
//
#include <hip/hip_runtime.h>
#include <math.h>

#define NODES   131072
#define EDGES   1048576
#define FDIM    32
#define HDIM    128
#define NGRAPH  512

#define NB      64          // coarse buckets
#define BSH     11          // tgt>>11 -> bucket; 2048 nodes per bucket
#define MAXPER  20480       // slots per coarse bucket in scratch
#define EPB     4096        // edges per kp1 block

typedef __attribute__((ext_vector_type(8))) short short8v;
typedef __attribute__((ext_vector_type(4))) float float4v;
typedef __attribute__((ext_vector_type(2))) float float2v;

__device__ __forceinline__ unsigned short f2bf(float f) {
    union { float f; unsigned int u; } v; v.f = f;
    unsigned int u = v.u;
    unsigned int r = (u + 0x7fffu + ((u >> 16) & 1u)) >> 16;   // RNE
    return (unsigned short)r;
}
__device__ __forceinline__ float bf2f(unsigned short u) {
    union { unsigned int u; float f; } v; v.u = ((unsigned int)u) << 16; return v.f;
}

// ---------------------------------------------------------------- k1: MFMA projection
__global__ __launch_bounds__(256) void k1_mfma(const float* __restrict__ x,
                                               const unsigned short* __restrict__ winfrag,
                                               unsigned char* __restrict__ h0f8,
                                               unsigned short* __restrict__ h0p) {
    int b = blockIdx.x, t = threadIdx.x;
    int wid = t >> 6, l = t & 63;
    int base = b * 128;

    const short8v* wf8 = (const short8v*)winfrag;
    short8v wfr[8];
#pragma unroll
    for (int c = 0; c < 8; ++c) wfr[c] = wf8[c * 64 + l];

#pragma unroll
    for (int s = 0; s < 2; ++s) {
        int strip = base + wid * 32 + s * 16;
        int row = strip + (l & 15);
        const float* xr = x + (size_t)row * FDIM + (l >> 4) * 8;
        float4 x0 = ((const float4*)xr)[0];
        float4 x1 = ((const float4*)xr)[1];
        short8v af;
        af[0] = (short)f2bf(x0.x); af[1] = (short)f2bf(x0.y);
        af[2] = (short)f2bf(x0.z); af[3] = (short)f2bf(x0.w);
        af[4] = (short)f2bf(x1.x); af[5] = (short)f2bf(x1.y);
        af[6] = (short)f2bf(x1.z); af[7] = (short)f2bf(x1.w);

        float4v acc[8];
#pragma unroll
        for (int c = 0; c < 8; ++c) acc[c] = (float4v){0.f, 0.f, 0.f, 0.f};
#pragma unroll
        for (int c = 0; c < 8; ++c)
            acc[c] = __builtin_amdgcn_mfma_f32_16x16x32_bf16(af, wfr[c], acc[c], 0, 0, 0);

        int rbase = strip + (l >> 4) * 4;   // C/D: col = lane&15, row = (lane>>4)*4 + reg
        int m = l & 15;
#pragma unroll
        for (int r = 0; r < 4; ++r) {
            int w0 = __builtin_amdgcn_cvt_pk_fp8_f32(acc[0][r], acc[1][r], 0, false);
            w0     = __builtin_amdgcn_cvt_pk_fp8_f32(acc[2][r], acc[3][r], w0, true);
            int w1 = __builtin_amdgcn_cvt_pk_fp8_f32(acc[4][r], acc[5][r], 0, false);
            w1     = __builtin_amdgcn_cvt_pk_fp8_f32(acc[6][r], acc[7][r], w1, true);
            *((uint2*)(h0f8 + (size_t)(rbase + r) * HDIM + m * 8)) = make_uint2((unsigned)w0, (unsigned)w1);
        }
        short8v* pp = (short8v*)(h0p + (size_t)strip * HDIM + l * 32);
#pragma unroll
        for (int r = 0; r < 4; ++r) {
            short8v v;
#pragma unroll
            for (int c = 0; c < 8; ++c) v[c] = (short)f2bf(acc[c][r]);
            pp[r] = v;
        }
    }
}

// ---------------------------------------------------------------- kp1: coarse partition
__global__ __launch_bounds__(256) void kp1_partition(const int* __restrict__ ei,
                                                     const float* __restrict__ ew,
                                                     int* __restrict__ coarse_cursor,
                                                     uint2* __restrict__ scratch) {
    __shared__ int hist[NB];
    __shared__ int excl[NB];
    __shared__ int gb[NB];
    __shared__ __align__(16) uint2 recL[EPB];
    __shared__ unsigned char bidL[EPB];

    int t = threadIdx.x;
    int e0 = blockIdx.x * EPB;

    if (t < NB) hist[t] = 0;
    __syncthreads();

    unsigned int rx[16]; unsigned int rw[16];
    int bb[16]; int lr[16];
#pragma unroll
    for (int i = 0; i < 16; ++i) {
        int e = e0 + t + 256 * i;
        int src = ei[e];
        int tgt = ei[EDGES + e];
        float w = ew[e];
        int bk = tgt >> BSH;
        rx[i] = (unsigned int)src | ((unsigned int)(tgt & ((1 << BSH) - 1)) << 17);
        rw[i] = __float_as_uint(w);
        bb[i] = bk;
        lr[i] = atomicAdd(&hist[bk], 1);
    }
    __syncthreads();

    if (t == 0) {
        int s = 0;
#pragma unroll
        for (int k = 0; k < NB; ++k) { excl[k] = s; s += hist[k]; }
    }
    __syncthreads();
    if (t < NB) gb[t] = atomicAdd(&coarse_cursor[t], hist[t]);
    __syncthreads();

#pragma unroll
    for (int i = 0; i < 16; ++i) {
        int pos = excl[bb[i]] + lr[i];
        recL[pos] = make_uint2(rx[i], rw[i]);
        bidL[pos] = (unsigned char)bb[i];
    }
    __syncthreads();

#pragma unroll
    for (int i = 0; i < 16; ++i) {
        int p = t + 256 * i;
        int bk = bidL[p];
        int dst = bk * MAXPER + gb[bk] + (p - excl[bk]);
        scratch[dst] = recL[p];
    }
}

// ---------------------------------------------------------------- kp2: fine CSR within coarse bucket
__global__ __launch_bounds__(256) void kp2_fine(const uint2* __restrict__ scratch,
                                                const int* __restrict__ coarse_cursor,
                                                int2* __restrict__ nbe,
                                                int2* __restrict__ csre) {
    __shared__ int fh[2048];
    __shared__ int ts[256];
    __shared__ int cc[NB];
    __shared__ int cpre[NB];

    int b = blockIdx.x, t = threadIdx.x;

    if (t < NB) cc[t] = coarse_cursor[t];
    for (int i = t; i < 2048; i += 256) fh[i] = 0;
    __syncthreads();
    if (t == 0) {
        int s = 0;
#pragma unroll
        for (int k = 0; k < NB; ++k) { cpre[k] = s; s += cc[k]; }
    }
    __syncthreads();

    int cnt_b = cc[b];
    int gbase = cpre[b];
    const uint2* src = scratch + (size_t)b * MAXPER;

    for (int j = t; j < cnt_b; j += 256) {
        uint2 r = src[j];
        atomicAdd(&fh[r.x >> 17], 1);
    }
    __syncthreads();

    int loc[8]; int s = 0;
#pragma unroll
    for (int q = 0; q < 8; ++q) { loc[q] = s; s += fh[t * 8 + q]; }
    ts[t] = s;
    __syncthreads();
    for (int off = 1; off < 256; off <<= 1) {
        int v = (t >= off) ? ts[t - off] : 0;
        __syncthreads();
        ts[t] += v;
        __syncthreads();
    }
    int tbase = ts[t] - s;

#pragma unroll
    for (int q = 0; q < 8; ++q) {
        int nl = t * 8 + q;
        int cntn = fh[nl];
        int beg = gbase + tbase + loc[q];
        nbe[b * 2048 + nl] = make_int2(beg, beg + cntn);
    }
    __syncthreads();
#pragma unroll
    for (int q = 0; q < 8; ++q) fh[t * 8 + q] = gbase + tbase + loc[q];
    __syncthreads();

    for (int j = t; j < cnt_b; j += 256) {
        uint2 r = src[j];
        int pos = atomicAdd(&fh[r.x >> 17], 1);
        csre[pos] = make_int2((int)(r.x & 0x1FFFFu), (int)r.y);
    }
}

// ---------------------------------------------------------------- prep
__global__ __launch_bounds__(256) void kprep(const float* __restrict__ Wmsg,
                                             const float* __restrict__ Win,
                                             unsigned short* __restrict__ wfrag,
                                             unsigned short* __restrict__ winfrag,
                                             const int* __restrict__ batch,
                                             int* __restrict__ cnt,
                                             float* __restrict__ gsum,
                                             int* __restrict__ coarse_cursor) {
    int b = blockIdx.x, t = threadIdx.x;
    if (b < 8) {
        int flat = b * 256 + t;
        int l = flat & 63;
        int fragid = flat >> 6;
        int c = fragid >> 2, kk = fragid & 3;
        int col = c * 16 + (l & 15);
        short8v v;
#pragma unroll
        for (int j = 0; j < 8; ++j) {
            int q = kk * 32 + (l >> 4) * 8 + j;          // position-space k
            int krow = (q & 7) * 16 + (q >> 3);          // true k = kappa(q)
            v[j] = (short)f2bf(Wmsg[krow * HDIM + col]);
        }
        ((short8v*)wfrag)[flat] = v;
    } else if (b < 10) {
        int flat = (b - 8) * 256 + t;
        int l = flat & 63;
        int c = flat >> 6;
        int col = c * 16 + (l & 15);
        int k0 = (l >> 4) * 8;
        short8v v;
#pragma unroll
        for (int j = 0; j < 8; ++j)
            v[j] = (short)f2bf(Win[(k0 + j) * HDIM + col]);
        ((short8v*)winfrag)[flat] = v;
    } else if (b < 12) {
        int g = (b - 10) * 256 + t;
        if (g < NGRAPH) {
            int lo = 0, hi = NODES;
            while (lo < hi) { int m = (lo + hi) >> 1; if (batch[m] < g) lo = m + 1; else hi = m; }
            int start = lo;
            hi = NODES;
            while (lo < hi) { int m = (lo + hi) >> 1; if (batch[m] < g + 1) lo = m + 1; else hi = m; }
            cnt[g] = lo - start;
        }
    } else if (b < 14) {
        float4* gz = (float4*)gsum;
        int idx = (b - 12) * 256 + t;
        for (int i = idx; i < 16384; i += 512) gz[i] = make_float4(0.f, 0.f, 0.f, 0.f);
    } else {
        if (t < NB) coarse_cursor[t] = 0;
    }
}

// ---------------------------------------------------------------- gather: 4 nodes per wave, 16 lanes/node
// lane = (grp = l>>4 -> node stream, m = l&15 -> uint2 of 8 fp8 positions m*8..m*8+7)
#define ACC8(r, w) do { \
    float2v q01 = __builtin_amdgcn_cvt_pk_f32_fp8((int)(r).x, false); \
    float2v q23 = __builtin_amdgcn_cvt_pk_f32_fp8((int)(r).x, true);  \
    float2v q45 = __builtin_amdgcn_cvt_pk_f32_fp8((int)(r).y, false); \
    float2v q67 = __builtin_amdgcn_cvt_pk_f32_fp8((int)(r).y, true);  \
    acc0 = fmaf(q01.x, (w), acc0); acc1 = fmaf(q01.y, (w), acc1); \
    acc2 = fmaf(q23.x, (w), acc2); acc3 = fmaf(q23.y, (w), acc3); \
    acc4 = fmaf(q45.x, (w), acc4); acc5 = fmaf(q45.y, (w), acc5); \
    acc6 = fmaf(q67.x, (w), acc6); acc7 = fmaf(q67.y, (w), acc7); \
} while (0)

__global__ __launch_bounds__(256) void kg_gather(const unsigned char* __restrict__ h0f8,
                                                 const int2* __restrict__ nbe,
                                                 const int2* __restrict__ csre,
                                                 unsigned short* __restrict__ msgb, int N) {
    int t = threadIdx.x;
    int wid = t >> 6, l = t & 63;
    int grp = l >> 4, m = l & 15;
    int n = blockIdx.x * 16 + wid * 4 + grp;

    int2 be = nbe[n];
    int j = be.x, end = be.y;
    float acc0 = 0.f, acc1 = 0.f, acc2 = 0.f, acc3 = 0.f;
    float acc4 = 0.f, acc5 = 0.f, acc6 = 0.f, acc7 = 0.f;

    for (; j + 4 <= end; j += 4) {
        int2 e0 = csre[j], e1 = csre[j + 1], e2 = csre[j + 2], e3 = csre[j + 3];
        uint2 r0 = ((const uint2*)(h0f8 + (size_t)e0.x * HDIM))[m];
        uint2 r1 = ((const uint2*)(h0f8 + (size_t)e1.x * HDIM))[m];
        uint2 r2 = ((const uint2*)(h0f8 + (size_t)e2.x * HDIM))[m];
        uint2 r3 = ((const uint2*)(h0f8 + (size_t)e3.x * HDIM))[m];
        float w0 = __int_as_float(e0.y), w1 = __int_as_float(e1.y);
        float w2 = __int_as_float(e2.y), w3 = __int_as_float(e3.y);
        ACC8(r0, w0); ACC8(r1, w1); ACC8(r2, w2); ACC8(r3, w3);
    }
    for (; j < end; ++j) {
        int2 e0 = csre[j];
        uint2 r0 = ((const uint2*)(h0f8 + (size_t)e0.x * HDIM))[m];
        float w0 = __int_as_float(e0.y);
        ACC8(r0, w0);
    }

    short8v v;
    v[0] = (short)f2bf(acc0); v[1] = (short)f2bf(acc1);
    v[2] = (short)f2bf(acc2); v[3] = (short)f2bf(acc3);
    v[4] = (short)f2bf(acc4); v[5] = (short)f2bf(acc5);
    v[6] = (short)f2bf(acc6); v[7] = (short)f2bf(acc7);
    ((short8v*)(msgb + (size_t)n * HDIM))[m] = v;
}

// ---------------------------------------------------------------- k3a: MFMA GEMM + relu + pool
__global__ __launch_bounds__(256) void k3a_mfma_pool(const unsigned short* __restrict__ msgb,
                                                     const unsigned short* __restrict__ h0p,
                                                     const unsigned short* __restrict__ wfrag,
                                                     const int* __restrict__ batch,
                                                     float* __restrict__ gsum) {
    __shared__ __align__(16) unsigned short blds[32 * 64 * 8];  // 32KB
    __shared__ float pool[8][HDIM];
    __shared__ int batch_lds[128];

    int t = threadIdx.x;
    int wid = t >> 6, l = t & 63;
    int base = blockIdx.x * 128;

    {
        const uint4* sp = (const uint4*)wfrag;
        uint4* d = (uint4*)blds;
#pragma unroll
        for (int i = 0; i < 8; ++i) d[t + 256 * i] = sp[t + 256 * i];
    }
    if (t < 128) batch_lds[t] = batch[base + t];
    __syncthreads();

    int bfirst = batch_lds[0];
    int blast  = batch_lds[127];
    int span = blast - bfirst + 1;

    const short8v* Bl = (const short8v*)blds;
    int col = l & 15;

    if (span <= 2) {
        float pa[8], pb[8];
#pragma unroll
        for (int c = 0; c < 8; ++c) { pa[c] = 0.f; pb[c] = 0.f; }

#pragma unroll
        for (int s = 0; s < 2; ++s) {
            int strip = base + wid * 32 + s * 16;
            const short8v* mrow = (const short8v*)(msgb + (size_t)(strip + col) * HDIM);
            short8v af[4];
#pragma unroll
            for (int kk = 0; kk < 4; ++kk) af[kk] = mrow[kk * 4 + (l >> 4)];
            const short8v* hp = (const short8v*)(h0p + (size_t)strip * HDIM + l * 32);
            short8v h0r[4];
#pragma unroll
            for (int r = 0; r < 4; ++r) h0r[r] = hp[r];

            float4v acc[8];
#pragma unroll
            for (int c = 0; c < 8; ++c) acc[c] = (float4v){0.f, 0.f, 0.f, 0.f};
#pragma unroll
            for (int kk = 0; kk < 4; ++kk)
#pragma unroll
                for (int c = 0; c < 8; ++c)
                    acc[c] = __builtin_amdgcn_mfma_f32_16x16x32_bf16(af[kk], Bl[(c * 4 + kk) * 64 + l], acc[c], 0, 0, 0);

            int rbase = strip + (l >> 4) * 4;
#pragma unroll
            for (int r = 0; r < 4; ++r) {
                bool isA = (batch_lds[rbase + r - base] == bfirst);
#pragma unroll
                for (int c = 0; c < 8; ++c) {
                    float hv = fmaxf(bf2f((unsigned short)h0r[r][c]) + acc[c][r], 0.f);
                    pa[c] += isA ? hv : 0.f;
                    pb[c] += isA ? 0.f : hv;
                }
            }
        }
#pragma unroll
        for (int c = 0; c < 8; ++c) {
            pa[c] += __shfl_xor(pa[c], 16);
            pa[c] += __shfl_xor(pa[c], 32);
            pb[c] += __shfl_xor(pb[c], 16);
            pb[c] += __shfl_xor(pb[c], 32);
        }
        float (*p2)[2][HDIM] = (float (*)[2][HDIM])pool;
        if (l < 16) {
#pragma unroll
            for (int c = 0; c < 8; ++c) {
                p2[wid][0][c * 16 + l] = pa[c];
                p2[wid][1][c * 16 + l] = pb[c];
            }
        }
        __syncthreads();
        int cc2 = t & 127, sidx = t >> 7;
        if (sidx < span) {
            float v = p2[0][sidx][cc2] + p2[1][sidx][cc2] + p2[2][sidx][cc2] + p2[3][sidx][cc2];
            atomicAdd(&gsum[(size_t)(bfirst + sidx) * HDIM + cc2], v);
        }
    } else {
        bool lds_pool = (span <= 8);
        if (lds_pool) {
            float* pf = (float*)pool;
            for (int i = t; i < 8 * HDIM; i += 256) pf[i] = 0.f;
        }
        __syncthreads();

        int rsub = (l >> 4) * 4;
#pragma unroll
        for (int s = 0; s < 2; ++s) {
            int strip = base + wid * 32 + s * 16;
            const short8v* mrow = (const short8v*)(msgb + (size_t)(strip + col) * HDIM);
            short8v af[4];
#pragma unroll
            for (int kk = 0; kk < 4; ++kk) af[kk] = mrow[kk * 4 + (l >> 4)];
            const short8v* hp = (const short8v*)(h0p + (size_t)strip * HDIM + l * 32);
            short8v h0r[4];
#pragma unroll
            for (int r = 0; r < 4; ++r) h0r[r] = hp[r];

            float4v acc[8];
#pragma unroll
            for (int c = 0; c < 8; ++c) acc[c] = (float4v){0.f, 0.f, 0.f, 0.f};
#pragma unroll
            for (int kk = 0; kk < 4; ++kk)
#pragma unroll
                for (int c = 0; c < 8; ++c)
                    acc[c] = __builtin_amdgcn_mfma_f32_16x16x32_bf16(af[kk], Bl[(c * 4 + kk) * 64 + l], acc[c], 0, 0, 0);

            int rbase = strip + rsub;
            if (lds_pool) {
#pragma unroll
                for (int r = 0; r < 4; ++r) {
                    int g = batch_lds[rbase + r - base] - bfirst;
#pragma unroll
                    for (int c = 0; c < 8; ++c) {
                        float hv = fmaxf(bf2f((unsigned short)h0r[r][c]) + acc[c][r], 0.f);
                        atomicAdd(&pool[g][c * 16 + col], hv);
                    }
                }
            } else {
#pragma unroll
                for (int r = 0; r < 4; ++r) {
                    int g = batch_lds[rbase + r - base];
#pragma unroll
                    for (int c = 0; c < 8; ++c) {
                        float hv = fmaxf(bf2f((unsigned short)h0r[r][c]) + acc[c][r], 0.f);
                        atomicAdd(&gsum[(size_t)g * HDIM + c * 16 + col], hv);
                    }
                }
            }
        }
        __syncthreads();
        if (lds_pool) {
            int cc2 = t & 127;
            for (int s2 = t >> 7; s2 < span; s2 += 2)
                atomicAdd(&gsum[(size_t)(bfirst + s2) * HDIM + cc2], pool[s2][cc2]);
        }
    }
}

// ---------------------------------------------------------------- k4a: backbone + value head
__global__ __launch_bounds__(128) void k4a_backbone(const float* __restrict__ gsum,
                                                    const int* __restrict__ cnt,
                                                    const float* __restrict__ W1,
                                                    const float* __restrict__ W2,
                                                    const float* __restrict__ Wv1,
                                                    const float* __restrict__ Wv2,
                                                    float* __restrict__ s2g,
                                                    float* __restrict__ out) {
    int g = blockIdx.x;
    int t = threadIdx.x;
    __shared__ float gv[HDIM];
    __shared__ float s1[HDIM];
    __shared__ float s2v[64];
    __shared__ float v1[32];

    {
        int c = cnt[g];
        gv[t] = (c > 0) ? gsum[(size_t)g * HDIM + t] / (float)c : 0.f;
    }
    __syncthreads();

    {
        float s = 0.f;
#pragma unroll 8
        for (int k = 0; k < HDIM; ++k)
            s = fmaf(gv[k], W1[k * HDIM + t] + W1[(k + HDIM) * HDIM + t], s);
        s1[t] = fmaxf(s, 0.f);
    }
    __syncthreads();

    if (t < 64) {
        float s = 0.f;
#pragma unroll 8
        for (int k = 0; k < HDIM; ++k)
            s = fmaf(s1[k], W2[k * 64 + t], s);
        float sv = fmaxf(s, 0.f);
        s2v[t] = sv;
        s2g[(size_t)g * 64 + t] = sv;
    }
    __syncthreads();

    if (t < 32) {
        float s = 0.f;
#pragma unroll 8
        for (int k = 0; k < 64; ++k)
            s = fmaf(s2v[k], Wv1[k * 32 + t], s);
        v1[t] = fmaxf(s, 0.f);
    }
    __syncthreads();
    if (t == 0) {
        float s = 0.f;
#pragma unroll
        for (int k = 0; k < 32; ++k)
            s = fmaf(v1[k], Wv2[k], s);
        out[1028608 + (size_t)g] = tanhf(s);
    }
}

// ---------------------------------------------------------------- k4b: logits GEMM [512,64]@[64,2009]
__global__ __launch_bounds__(256) void k4b_logits(const float* __restrict__ s2g,
                                                  const float* __restrict__ Wa,
                                                  const float* __restrict__ Ws,
                                                  const float* __restrict__ Wt,
                                                  const float* __restrict__ Wact,
                                                  float* __restrict__ out) {
    int ctile = blockIdx.x & 7;
    int gbase = (blockIdx.x >> 3) * 16;
    int t = threadIdx.x;
    int col = ctile * 256 + t;

    __shared__ float4 s2s4[16][16];
    {
        int g = t >> 4, q = t & 15;
        s2s4[g][q] = ((const float4*)(s2g + (size_t)(gbase + g) * 64))[q];
    }

    bool valid = (col < 2009);
    const float* W = Wa; int colc = 0, ncol = 5; size_t hb = 0;
    if (col < 5)        { W = Wa;   colc = col;        ncol = 5;    hb = 0; }
    else if (col < 1005){ W = Ws;   colc = col - 5;    ncol = 1000; hb = 2560; }
    else if (col < 2005){ W = Wt;   colc = col - 1005; ncol = 1000; hb = 514560; }
    else                { W = Wact; colc = col - 2005; ncol = 4;    hb = 1026560; }

    float wr[64];
#pragma unroll
    for (int k = 0; k < 64; ++k)
        wr[k] = valid ? W[(size_t)k * ncol + colc] : 0.f;
    __syncthreads();

    for (int gg = 0; gg < 16; ++gg) {
        const float4* s4 = (const float4*)s2s4[gg];
        float a = 0.f;
#pragma unroll
        for (int q = 0; q < 16; ++q) {
            float4 v = s4[q];
            a = fmaf(v.x, wr[4 * q + 0], a);
            a = fmaf(v.y, wr[4 * q + 1], a);
            a = fmaf(v.z, wr[4 * q + 2], a);
            a = fmaf(v.w, wr[4 * q + 3], a);
        }
        if (valid) out[hb + (size_t)(gbase + gg) * ncol + colc] = a;
    }
}

// ----------------------------------------------------------------
extern "C" void kernel_launch(void* const* d_in, const int* in_sizes, int n_in,
                              void* d_out, int out_size, void* d_ws, size_t ws_size,
                              hipStream_t stream) {
    const float* x     = (const float*)d_in[0];
    const int*   ei    = (const int*)d_in[1];
    const float* ew    = (const float*)d_in[2];
    const int*   batch = (const int*)d_in[4];
    const float* Win   = (const float*)d_in[6];
    const float* Wmsg  = (const float*)d_in[7];
    const float* W1    = (const float*)d_in[8];
    const float* W2    = (const float*)d_in[9];
    const float* Wa    = (const float*)d_in[10];
    const float* Ws    = (const float*)d_in[11];
    const float* Wt    = (const float*)d_in[12];
    const float* Wact  = (const float*)d_in[13];
    const float* Wv1   = (const float*)d_in[14];
    const float* Wv2   = (const float*)d_in[15];
    float* out = (float*)d_out;

    char* p = (char*)d_ws;
    const size_t nb = (size_t)NODES * HDIM * 2;                  // 32 MB
    unsigned char*  h0f8   = (unsigned char*)p;   p += (size_t)NODES * HDIM;   // 16 MB
    unsigned short* msgb   = (unsigned short*)p;  p += nb;
    unsigned short* h0p    = (unsigned short*)p;  p += nb;
    float*          gsum   = (float*)p;           p += (size_t)NGRAPH * HDIM * 4;
    float*          s2g    = (float*)p;           p += (size_t)NGRAPH * 64 * 4;
    unsigned short* wfrag  = (unsigned short*)p;  p += 32 * 64 * 16;
    unsigned short* winfrag= (unsigned short*)p;  p += 8 * 64 * 16;
    int*            cnt    = (int*)p;             p += (size_t)NGRAPH * 4;
    int*            ccur   = (int*)p;             p += 256;
    uint2*          scratch= (uint2*)p;           p += (size_t)NB * MAXPER * 8;
    int2*           nbe    = (int2*)p;            p += (size_t)NODES * 8;
    int2*           csre   = (int2*)p;            p += (size_t)EDGES * 8;

    kprep        <<<15, 256, 0, stream>>>(Wmsg, Win, wfrag, winfrag, batch, cnt, gsum, ccur);
    k1_mfma      <<<1024, 256, 0, stream>>>(x, winfrag, h0f8, h0p);
    kp1_partition<<<EDGES / EPB, 256, 0, stream>>>(ei, ew, ccur, scratch);
    kp2_fine     <<<NB, 256, 0, stream>>>(scratch, ccur, nbe, csre);

    kg_gather    <<<NODES / 16, 256, 0, stream>>>(h0f8, nbe, csre, msgb, NODES);

    k3a_mfma_pool<<<NODES / 128, 256, 0, stream>>>(msgb, h0p, wfrag, batch, gsum);

    k4a_backbone <<<NGRAPH, 128, 0, stream>>>(gsum, cnt, W1, W2, Wv1, Wv2, s2g, out);
    k4b_logits   <<<256, 256, 0, stream>>>(s2g, Wa, Ws, Wt, Wact, out);
}

// Round 12
// 112.954 us; speedup vs baseline: 2.9024x; 1.3578x over previous
//
#include <hip/hip_runtime.h>
#include <math.h>

#define NODES   131072
#define EDGES   1048576
#define FDIM    32
#define HDIM    128
#define NGRAPH  512

#define NB      256         // coarse buckets
#define BSH     9           // tgt>>9 -> bucket; 512 nodes per bucket
#define MAXPER  5120        // slots per bucket (avg 4096 + 16 sigma)
#define EPB     4096        // edges per partition block

typedef __attribute__((ext_vector_type(8))) short short8v;
typedef __attribute__((ext_vector_type(4))) float float4v;
typedef __attribute__((ext_vector_type(2))) float float2v;

__device__ __forceinline__ unsigned short f2bf(float f) {
    union { float f; unsigned int u; } v; v.f = f;
    unsigned int u = v.u;
    unsigned int r = (u + 0x7fffu + ((u >> 16) & 1u)) >> 16;   // RNE
    return (unsigned short)r;
}

// decode 8 fp8 (positions m*8..m*8+7) -> true cols c*16+m for c=0..7
__device__ __forceinline__ void dec8(uint2 r, float* o) {
    float2v a = __builtin_amdgcn_cvt_pk_f32_fp8((int)r.x, false);
    float2v b = __builtin_amdgcn_cvt_pk_f32_fp8((int)r.x, true);
    float2v c = __builtin_amdgcn_cvt_pk_f32_fp8((int)r.y, false);
    float2v d = __builtin_amdgcn_cvt_pk_f32_fp8((int)r.y, true);
    o[0] = a.x; o[1] = a.y; o[2] = b.x; o[3] = b.y;
    o[4] = c.x; o[5] = c.y; o[6] = d.x; o[7] = d.y;
}

// ---------------------------------------------------------------- k1_fused: [0,NB) edge partition | [NB,NB+1024) MFMA projection
__global__ __launch_bounds__(256) void k1_fused(const float* __restrict__ x,
                                                const unsigned short* __restrict__ winfrag,
                                                unsigned char* __restrict__ h0f8,
                                                const int* __restrict__ ei,
                                                const float* __restrict__ ew,
                                                int* __restrict__ coarse_cursor,
                                                uint2* __restrict__ scratch) {
    __shared__ __align__(16) uint2 recL[EPB];     // 32KB
    __shared__ unsigned char bidL[EPB];           // 4KB
    __shared__ int hist[NB];
    __shared__ int excl[NB];
    __shared__ int gb[NB];

    int b = blockIdx.x, t = threadIdx.x;

    if (b < NB) {
        // ---- coarse partition block
        int e0 = b * EPB;
        hist[t] = 0;
        __syncthreads();

        unsigned int rx[16], rw[16];
        int bb[16], lr[16];
#pragma unroll
        for (int i = 0; i < 16; ++i) {
            int e = e0 + t + 256 * i;
            int src = ei[e];
            int tgt = ei[EDGES + e];
            float w = ew[e];
            int bk = tgt >> BSH;
            rx[i] = (unsigned int)src | ((unsigned int)(tgt & ((1 << BSH) - 1)) << 17);
            rw[i] = __float_as_uint(w);
            bb[i] = bk;
            lr[i] = atomicAdd(&hist[bk], 1);
        }
        __syncthreads();

        // parallel exclusive scan of hist -> excl
        int hv = hist[t];
        excl[t] = hv;
        __syncthreads();
        for (int off = 1; off < 256; off <<= 1) {
            int v = (t >= off) ? excl[t - off] : 0;
            __syncthreads();
            excl[t] += v;
            __syncthreads();
        }
        int ex = excl[t] - hv;
        gb[t] = atomicAdd(&coarse_cursor[t], hv);
        __syncthreads();
        excl[t] = ex;
        __syncthreads();

#pragma unroll
        for (int i = 0; i < 16; ++i) {
            int pos = excl[bb[i]] + lr[i];
            recL[pos] = make_uint2(rx[i], rw[i]);
            bidL[pos] = (unsigned char)bb[i];
        }
        __syncthreads();

#pragma unroll
        for (int i = 0; i < 16; ++i) {
            int p2 = t + 256 * i;
            int bk = bidL[p2];
            int dst = bk * MAXPER + gb[bk] + (p2 - excl[bk]);
            scratch[dst] = recL[p2];
        }
    } else {
        // ---- MFMA projection block
        int mb = b - NB;
        int wid = t >> 6, l = t & 63;
        int base = mb * 128;

        const short8v* wf8 = (const short8v*)winfrag;
        short8v wfr[8];
#pragma unroll
        for (int c = 0; c < 8; ++c) wfr[c] = wf8[c * 64 + l];

#pragma unroll
        for (int s = 0; s < 2; ++s) {
            int strip = base + wid * 32 + s * 16;
            int row = strip + (l & 15);
            const float* xr = x + (size_t)row * FDIM + (l >> 4) * 8;
            float4 x0 = ((const float4*)xr)[0];
            float4 x1 = ((const float4*)xr)[1];
            short8v af;
            af[0] = (short)f2bf(x0.x); af[1] = (short)f2bf(x0.y);
            af[2] = (short)f2bf(x0.z); af[3] = (short)f2bf(x0.w);
            af[4] = (short)f2bf(x1.x); af[5] = (short)f2bf(x1.y);
            af[6] = (short)f2bf(x1.z); af[7] = (short)f2bf(x1.w);

            float4v acc[8];
#pragma unroll
            for (int c = 0; c < 8; ++c) acc[c] = (float4v){0.f, 0.f, 0.f, 0.f};
#pragma unroll
            for (int c = 0; c < 8; ++c)
                acc[c] = __builtin_amdgcn_mfma_f32_16x16x32_bf16(af, wfr[c], acc[c], 0, 0, 0);

            int rbase = strip + (l >> 4) * 4;
            int m = l & 15;
#pragma unroll
            for (int r = 0; r < 4; ++r) {
                int w0 = __builtin_amdgcn_cvt_pk_fp8_f32(acc[0][r], acc[1][r], 0, false);
                w0     = __builtin_amdgcn_cvt_pk_fp8_f32(acc[2][r], acc[3][r], w0, true);
                int w1 = __builtin_amdgcn_cvt_pk_fp8_f32(acc[4][r], acc[5][r], 0, false);
                w1     = __builtin_amdgcn_cvt_pk_fp8_f32(acc[6][r], acc[7][r], w1, true);
                *((uint2*)(h0f8 + (size_t)(rbase + r) * HDIM + m * 8)) = make_uint2((unsigned)w0, (unsigned)w1);
            }
        }
    }
}

// ---------------------------------------------------------------- kp2: fine CSR within coarse bucket (256 blocks)
__global__ __launch_bounds__(256) void kp2_fine(const uint2* __restrict__ scratch,
                                                const int* __restrict__ coarse_cursor,
                                                int2* __restrict__ nbe,
                                                int2* __restrict__ csre) {
    __shared__ int fh[512];       // fine hist -> cursor (512 nodes/bucket)
    __shared__ int ts[256];
    __shared__ int ccs[256];

    int b = blockIdx.x, t = threadIdx.x;

    ccs[t] = coarse_cursor[t];
    fh[t] = 0; fh[t + 256] = 0;
    __syncthreads();
    // inclusive scan of bucket counts for gbase
    for (int off = 1; off < 256; off <<= 1) {
        int v = (t >= off) ? ccs[t - off] : 0;
        __syncthreads();
        ccs[t] += v;
        __syncthreads();
    }
    int gbase = (b > 0) ? ccs[b - 1] : 0;
    int cnt_b = coarse_cursor[b];
    const uint2* src = scratch + (size_t)b * MAXPER;

    for (int j = t; j < cnt_b; j += 256) {
        uint2 r = src[j];
        atomicAdd(&fh[r.x >> 17], 1);
    }
    __syncthreads();

    // scan over 512 counts (2 per thread)
    int c0 = fh[2 * t], c1 = fh[2 * t + 1];
    int s = c0 + c1;
    ts[t] = s;
    __syncthreads();
    for (int off = 1; off < 256; off <<= 1) {
        int v = (t >= off) ? ts[t - off] : 0;
        __syncthreads();
        ts[t] += v;
        __syncthreads();
    }
    int tb = gbase + ts[t] - s;

    nbe[b * 512 + 2 * t]     = make_int2(tb, tb + c0);
    nbe[b * 512 + 2 * t + 1] = make_int2(tb + c0, tb + c0 + c1);
    __syncthreads();
    fh[2 * t] = tb; fh[2 * t + 1] = tb + c0;
    __syncthreads();

    for (int j = t; j < cnt_b; j += 256) {
        uint2 r = src[j];
        int pos = atomicAdd(&fh[r.x >> 17], 1);
        csre[pos] = make_int2((int)(r.x & 0x1FFFFu), (int)r.y);
    }
}

// ---------------------------------------------------------------- prep
__global__ __launch_bounds__(256) void kprep(const float* __restrict__ Wmsg,
                                             const float* __restrict__ Win,
                                             unsigned short* __restrict__ wfrag,
                                             unsigned short* __restrict__ winfrag,
                                             const int* __restrict__ batch,
                                             int* __restrict__ cnt,
                                             float* __restrict__ gsum,
                                             int* __restrict__ coarse_cursor) {
    int b = blockIdx.x, t = threadIdx.x;
    if (b < 8) {
        int flat = b * 256 + t;
        int l = flat & 63;
        int fragid = flat >> 6;
        int c = fragid >> 2, kk = fragid & 3;
        int col = c * 16 + (l & 15);
        short8v v;
#pragma unroll
        for (int j = 0; j < 8; ++j) {
            int q = kk * 32 + (l >> 4) * 8 + j;          // position-space k
            int krow = (q & 7) * 16 + (q >> 3);          // true k
            v[j] = (short)f2bf(Wmsg[krow * HDIM + col]);
        }
        ((short8v*)wfrag)[flat] = v;
    } else if (b < 10) {
        int flat = (b - 8) * 256 + t;
        int l = flat & 63;
        int c = flat >> 6;
        int col = c * 16 + (l & 15);
        int k0 = (l >> 4) * 8;
        short8v v;
#pragma unroll
        for (int j = 0; j < 8; ++j)
            v[j] = (short)f2bf(Win[(k0 + j) * HDIM + col]);
        ((short8v*)winfrag)[flat] = v;
    } else if (b < 12) {
        int g = (b - 10) * 256 + t;
        if (g < NGRAPH) {
            int lo = 0, hi = NODES;
            while (lo < hi) { int m = (lo + hi) >> 1; if (batch[m] < g) lo = m + 1; else hi = m; }
            int start = lo;
            hi = NODES;
            while (lo < hi) { int m = (lo + hi) >> 1; if (batch[m] < g + 1) lo = m + 1; else hi = m; }
            cnt[g] = lo - start;
        }
    } else if (b < 14) {
        float4* gz = (float4*)gsum;
        int idx = (b - 12) * 256 + t;
        for (int i = idx; i < 16384; i += 512) gz[i] = make_float4(0.f, 0.f, 0.f, 0.f);
    } else {
        coarse_cursor[t] = 0;
    }
}

// ---------------------------------------------------------------- gather: 4 nodes per wave, 16 lanes/node
#define ACC8(r, w) do { \
    float2v q01 = __builtin_amdgcn_cvt_pk_f32_fp8((int)(r).x, false); \
    float2v q23 = __builtin_amdgcn_cvt_pk_f32_fp8((int)(r).x, true);  \
    float2v q45 = __builtin_amdgcn_cvt_pk_f32_fp8((int)(r).y, false); \
    float2v q67 = __builtin_amdgcn_cvt_pk_f32_fp8((int)(r).y, true);  \
    acc0 = fmaf(q01.x, (w), acc0); acc1 = fmaf(q01.y, (w), acc1); \
    acc2 = fmaf(q23.x, (w), acc2); acc3 = fmaf(q23.y, (w), acc3); \
    acc4 = fmaf(q45.x, (w), acc4); acc5 = fmaf(q45.y, (w), acc5); \
    acc6 = fmaf(q67.x, (w), acc6); acc7 = fmaf(q67.y, (w), acc7); \
} while (0)

__global__ __launch_bounds__(256) void kg_gather(const unsigned char* __restrict__ h0f8,
                                                 const int2* __restrict__ nbe,
                                                 const int2* __restrict__ csre,
                                                 unsigned short* __restrict__ msgb, int N) {
    int t = threadIdx.x;
    int wid = t >> 6, l = t & 63;
    int grp = l >> 4, m = l & 15;
    int n = blockIdx.x * 16 + wid * 4 + grp;

    int2 be = nbe[n];
    int j = be.x, end = be.y;
    float acc0 = 0.f, acc1 = 0.f, acc2 = 0.f, acc3 = 0.f;
    float acc4 = 0.f, acc5 = 0.f, acc6 = 0.f, acc7 = 0.f;

    for (; j + 4 <= end; j += 4) {
        int2 e0 = csre[j], e1 = csre[j + 1], e2 = csre[j + 2], e3 = csre[j + 3];
        uint2 r0 = ((const uint2*)(h0f8 + (size_t)e0.x * HDIM))[m];
        uint2 r1 = ((const uint2*)(h0f8 + (size_t)e1.x * HDIM))[m];
        uint2 r2 = ((const uint2*)(h0f8 + (size_t)e2.x * HDIM))[m];
        uint2 r3 = ((const uint2*)(h0f8 + (size_t)e3.x * HDIM))[m];
        float w0 = __int_as_float(e0.y), w1 = __int_as_float(e1.y);
        float w2 = __int_as_float(e2.y), w3 = __int_as_float(e3.y);
        ACC8(r0, w0); ACC8(r1, w1); ACC8(r2, w2); ACC8(r3, w3);
    }
    for (; j < end; ++j) {
        int2 e0 = csre[j];
        uint2 r0 = ((const uint2*)(h0f8 + (size_t)e0.x * HDIM))[m];
        float w0 = __int_as_float(e0.y);
        ACC8(r0, w0);
    }

    short8v v;
    v[0] = (short)f2bf(acc0); v[1] = (short)f2bf(acc1);
    v[2] = (short)f2bf(acc2); v[3] = (short)f2bf(acc3);
    v[4] = (short)f2bf(acc4); v[5] = (short)f2bf(acc5);
    v[6] = (short)f2bf(acc6); v[7] = (short)f2bf(acc7);
    ((short8v*)(msgb + (size_t)n * HDIM))[m] = v;
}

// ---------------------------------------------------------------- k3a: MFMA GEMM + relu + pool (h0 term decoded from fp8)
__global__ __launch_bounds__(256) void k3a_mfma_pool(const unsigned short* __restrict__ msgb,
                                                     const unsigned char* __restrict__ h0f8,
                                                     const unsigned short* __restrict__ wfrag,
                                                     const int* __restrict__ batch,
                                                     float* __restrict__ gsum) {
    __shared__ __align__(16) unsigned short blds[32 * 64 * 8];  // 32KB
    __shared__ float pool[8][HDIM];
    __shared__ int batch_lds[128];

    int t = threadIdx.x;
    int wid = t >> 6, l = t & 63;
    int base = blockIdx.x * 128;

    {
        const uint4* sp = (const uint4*)wfrag;
        uint4* d = (uint4*)blds;
#pragma unroll
        for (int i = 0; i < 8; ++i) d[t + 256 * i] = sp[t + 256 * i];
    }
    if (t < 128) batch_lds[t] = batch[base + t];
    __syncthreads();

    int bfirst = batch_lds[0];
    int blast  = batch_lds[127];
    int span = blast - bfirst + 1;

    const short8v* Bl = (const short8v*)blds;
    int col = l & 15;

    if (span <= 2) {
        float pa[8], pb[8];
#pragma unroll
        for (int c = 0; c < 8; ++c) { pa[c] = 0.f; pb[c] = 0.f; }

#pragma unroll
        for (int s = 0; s < 2; ++s) {
            int strip = base + wid * 32 + s * 16;
            const short8v* mrow = (const short8v*)(msgb + (size_t)(strip + col) * HDIM);
            short8v af[4];
#pragma unroll
            for (int kk = 0; kk < 4; ++kk) af[kk] = mrow[kk * 4 + (l >> 4)];
            int rbase = strip + (l >> 4) * 4;
            uint2 h8[4];
#pragma unroll
            for (int r = 0; r < 4; ++r)
                h8[r] = *((const uint2*)(h0f8 + (size_t)(rbase + r) * HDIM + col * 8));

            float4v acc[8];
#pragma unroll
            for (int c = 0; c < 8; ++c) acc[c] = (float4v){0.f, 0.f, 0.f, 0.f};
#pragma unroll
            for (int kk = 0; kk < 4; ++kk)
#pragma unroll
                for (int c = 0; c < 8; ++c)
                    acc[c] = __builtin_amdgcn_mfma_f32_16x16x32_bf16(af[kk], Bl[(c * 4 + kk) * 64 + l], acc[c], 0, 0, 0);

#pragma unroll
            for (int r = 0; r < 4; ++r) {
                bool isA = (batch_lds[rbase + r - base] == bfirst);
                float h0v[8];
                dec8(h8[r], h0v);
#pragma unroll
                for (int c = 0; c < 8; ++c) {
                    float hv = fmaxf(h0v[c] + acc[c][r], 0.f);
                    pa[c] += isA ? hv : 0.f;
                    pb[c] += isA ? 0.f : hv;
                }
            }
        }
#pragma unroll
        for (int c = 0; c < 8; ++c) {
            pa[c] += __shfl_xor(pa[c], 16);
            pa[c] += __shfl_xor(pa[c], 32);
            pb[c] += __shfl_xor(pb[c], 16);
            pb[c] += __shfl_xor(pb[c], 32);
        }
        float (*p2)[2][HDIM] = (float (*)[2][HDIM])pool;
        if (l < 16) {
#pragma unroll
            for (int c = 0; c < 8; ++c) {
                p2[wid][0][c * 16 + l] = pa[c];
                p2[wid][1][c * 16 + l] = pb[c];
            }
        }
        __syncthreads();
        int cc2 = t & 127, sidx = t >> 7;
        if (sidx < span) {
            float v = p2[0][sidx][cc2] + p2[1][sidx][cc2] + p2[2][sidx][cc2] + p2[3][sidx][cc2];
            atomicAdd(&gsum[(size_t)(bfirst + sidx) * HDIM + cc2], v);
        }
    } else {
        bool lds_pool = (span <= 8);
        if (lds_pool) {
            float* pf = (float*)pool;
            for (int i = t; i < 8 * HDIM; i += 256) pf[i] = 0.f;
        }
        __syncthreads();

#pragma unroll
        for (int s = 0; s < 2; ++s) {
            int strip = base + wid * 32 + s * 16;
            const short8v* mrow = (const short8v*)(msgb + (size_t)(strip + col) * HDIM);
            short8v af[4];
#pragma unroll
            for (int kk = 0; kk < 4; ++kk) af[kk] = mrow[kk * 4 + (l >> 4)];
            int rbase = strip + (l >> 4) * 4;
            uint2 h8[4];
#pragma unroll
            for (int r = 0; r < 4; ++r)
                h8[r] = *((const uint2*)(h0f8 + (size_t)(rbase + r) * HDIM + col * 8));

            float4v acc[8];
#pragma unroll
            for (int c = 0; c < 8; ++c) acc[c] = (float4v){0.f, 0.f, 0.f, 0.f};
#pragma unroll
            for (int kk = 0; kk < 4; ++kk)
#pragma unroll
                for (int c = 0; c < 8; ++c)
                    acc[c] = __builtin_amdgcn_mfma_f32_16x16x32_bf16(af[kk], Bl[(c * 4 + kk) * 64 + l], acc[c], 0, 0, 0);

            if (lds_pool) {
#pragma unroll
                for (int r = 0; r < 4; ++r) {
                    int g = batch_lds[rbase + r - base] - bfirst;
                    float h0v[8];
                    dec8(h8[r], h0v);
#pragma unroll
                    for (int c = 0; c < 8; ++c) {
                        float hv = fmaxf(h0v[c] + acc[c][r], 0.f);
                        atomicAdd(&pool[g][c * 16 + col], hv);
                    }
                }
            } else {
#pragma unroll
                for (int r = 0; r < 4; ++r) {
                    int g = batch_lds[rbase + r - base];
                    float h0v[8];
                    dec8(h8[r], h0v);
#pragma unroll
                    for (int c = 0; c < 8; ++c) {
                        float hv = fmaxf(h0v[c] + acc[c][r], 0.f);
                        atomicAdd(&gsum[(size_t)g * HDIM + c * 16 + col], hv);
                    }
                }
            }
        }
        __syncthreads();
        if (lds_pool) {
            int cc2 = t & 127;
            for (int s2 = t >> 7; s2 < span; s2 += 2)
                atomicAdd(&gsum[(size_t)(bfirst + s2) * HDIM + cc2], pool[s2][cc2]);
        }
    }
}

// ---------------------------------------------------------------- k4a: backbone + value head
__global__ __launch_bounds__(128) void k4a_backbone(const float* __restrict__ gsum,
                                                    const int* __restrict__ cnt,
                                                    const float* __restrict__ W1,
                                                    const float* __restrict__ W2,
                                                    const float* __restrict__ Wv1,
                                                    const float* __restrict__ Wv2,
                                                    float* __restrict__ s2g,
                                                    float* __restrict__ out) {
    int g = blockIdx.x;
    int t = threadIdx.x;
    __shared__ float gv[HDIM];
    __shared__ float s1[HDIM];
    __shared__ float s2v[64];
    __shared__ float v1[32];

    {
        int c = cnt[g];
        gv[t] = (c > 0) ? gsum[(size_t)g * HDIM + t] / (float)c : 0.f;
    }
    __syncthreads();

    {
        float s = 0.f;
#pragma unroll 8
        for (int k = 0; k < HDIM; ++k)
            s = fmaf(gv[k], W1[k * HDIM + t] + W1[(k + HDIM) * HDIM + t], s);
        s1[t] = fmaxf(s, 0.f);
    }
    __syncthreads();

    if (t < 64) {
        float s = 0.f;
#pragma unroll 8
        for (int k = 0; k < HDIM; ++k)
            s = fmaf(s1[k], W2[k * 64 + t], s);
        float sv = fmaxf(s, 0.f);
        s2v[t] = sv;
        s2g[(size_t)g * 64 + t] = sv;
    }
    __syncthreads();

    if (t < 32) {
        float s = 0.f;
#pragma unroll 8
        for (int k = 0; k < 64; ++k)
            s = fmaf(s2v[k], Wv1[k * 32 + t], s);
        v1[t] = fmaxf(s, 0.f);
    }
    __syncthreads();
    if (t == 0) {
        float s = 0.f;
#pragma unroll
        for (int k = 0; k < 32; ++k)
            s = fmaf(v1[k], Wv2[k], s);
        out[1028608 + (size_t)g] = tanhf(s);
    }
}

// ---------------------------------------------------------------- k4b: logits GEMM [512,64]@[64,2009]
__global__ __launch_bounds__(256) void k4b_logits(const float* __restrict__ s2g,
                                                  const float* __restrict__ Wa,
                                                  const float* __restrict__ Ws,
                                                  const float* __restrict__ Wt,
                                                  const float* __restrict__ Wact,
                                                  float* __restrict__ out) {
    int ctile = blockIdx.x & 7;
    int gbase = (blockIdx.x >> 3) * 16;
    int t = threadIdx.x;
    int col = ctile * 256 + t;

    __shared__ float4 s2s4[16][16];
    {
        int g = t >> 4, q = t & 15;
        s2s4[g][q] = ((const float4*)(s2g + (size_t)(gbase + g) * 64))[q];
    }

    bool valid = (col < 2009);
    const float* W = Wa; int colc = 0, ncol = 5; size_t hb = 0;
    if (col < 5)        { W = Wa;   colc = col;        ncol = 5;    hb = 0; }
    else if (col < 1005){ W = Ws;   colc = col - 5;    ncol = 1000; hb = 2560; }
    else if (col < 2005){ W = Wt;   colc = col - 1005; ncol = 1000; hb = 514560; }
    else                { W = Wact; colc = col - 2005; ncol = 4;    hb = 1026560; }

    float wr[64];
#pragma unroll
    for (int k = 0; k < 64; ++k)
        wr[k] = valid ? W[(size_t)k * ncol + colc] : 0.f;
    __syncthreads();

    for (int gg = 0; gg < 16; ++gg) {
        const float4* s4 = (const float4*)s2s4[gg];
        float a = 0.f;
#pragma unroll
        for (int q = 0; q < 16; ++q) {
            float4 v = s4[q];
            a = fmaf(v.x, wr[4 * q + 0], a);
            a = fmaf(v.y, wr[4 * q + 1], a);
            a = fmaf(v.z, wr[4 * q + 2], a);
            a = fmaf(v.w, wr[4 * q + 3], a);
        }
        if (valid) out[hb + (size_t)(gbase + gg) * ncol + colc] = a;
    }
}

// ----------------------------------------------------------------
extern "C" void kernel_launch(void* const* d_in, const int* in_sizes, int n_in,
                              void* d_out, int out_size, void* d_ws, size_t ws_size,
                              hipStream_t stream) {
    const float* x     = (const float*)d_in[0];
    const int*   ei    = (const int*)d_in[1];
    const float* ew    = (const float*)d_in[2];
    const int*   batch = (const int*)d_in[4];
    const float* Win   = (const float*)d_in[6];
    const float* Wmsg  = (const float*)d_in[7];
    const float* W1    = (const float*)d_in[8];
    const float* W2    = (const float*)d_in[9];
    const float* Wa    = (const float*)d_in[10];
    const float* Ws    = (const float*)d_in[11];
    const float* Wt    = (const float*)d_in[12];
    const float* Wact  = (const float*)d_in[13];
    const float* Wv1   = (const float*)d_in[14];
    const float* Wv2   = (const float*)d_in[15];
    float* out = (float*)d_out;

    char* p = (char*)d_ws;
    const size_t nb = (size_t)NODES * HDIM * 2;                  // 32 MB
    unsigned char*  h0f8   = (unsigned char*)p;   p += (size_t)NODES * HDIM;   // 16 MB
    unsigned short* msgb   = (unsigned short*)p;  p += nb;
    float*          gsum   = (float*)p;           p += (size_t)NGRAPH * HDIM * 4;
    float*          s2g    = (float*)p;           p += (size_t)NGRAPH * 64 * 4;
    unsigned short* wfrag  = (unsigned short*)p;  p += 32 * 64 * 16;
    unsigned short* winfrag= (unsigned short*)p;  p += 8 * 64 * 16;
    int*            cnt    = (int*)p;             p += (size_t)NGRAPH * 4;
    int*            ccur   = (int*)p;             p += NB * 4;
    uint2*          scratch= (uint2*)p;           p += (size_t)NB * MAXPER * 8;   // 10.5 MB
    int2*           nbe    = (int2*)p;            p += (size_t)NODES * 8;
    int2*           csre   = (int2*)p;            p += (size_t)EDGES * 8;

    kprep        <<<15, 256, 0, stream>>>(Wmsg, Win, wfrag, winfrag, batch, cnt, gsum, ccur);
    k1_fused     <<<NB + 1024, 256, 0, stream>>>(x, winfrag, h0f8, ei, ew, ccur, scratch);
    kp2_fine     <<<NB, 256, 0, stream>>>(scratch, ccur, nbe, csre);

    kg_gather    <<<NODES / 16, 256, 0, stream>>>(h0f8, nbe, csre, msgb, NODES);

    k3a_mfma_pool<<<NODES / 128, 256, 0, stream>>>(msgb, h0f8, wfrag, batch, gsum);

    k4a_backbone <<<NGRAPH, 128, 0, stream>>>(gsum, cnt, W1, W2, Wv1, Wv2, s2g, out);
    k4b_logits   <<<256, 256, 0, stream>>>(s2g, Wa, Ws, Wt, Wact, out);
}